// Round 4
// baseline (361.618 us; speedup 1.0000x reference)
//
#include <hip/hip_runtime.h>

#define N_NODES 50000
#define N_EDGES 800000
#define N_LABEL 200000

typedef __attribute__((ext_vector_type(8))) short bf16x8;
typedef __attribute__((ext_vector_type(4))) float f32x4;

__device__ inline unsigned short f2bf_rne(float f) {
    union { float f; unsigned u; } v; v.f = f;
    unsigned r = v.u + 0x7fffu + ((v.u >> 16) & 1u);
    return (unsigned short)(r >> 16);
}
__device__ inline float bf2f(unsigned short h) {
    union { unsigned u; float f; } v; v.u = ((unsigned)h) << 16;
    return v.f;
}

// ---------------- CSR build ----------------
__global__ void k_zero2(int* a, int* b, int n) {
    int i = blockIdx.x * blockDim.x + threadIdx.x;
    if (i < n) { a[i] = 0; b[i] = 0; }
}

__global__ void k_deg_count(const int* __restrict__ dst, int* cnt, int E) {
    int i = blockIdx.x * blockDim.x + threadIdx.x;
    if (i < E) atomicAdd(&cnt[dst[i]], 1);
}

__global__ __launch_bounds__(256)
void k_partial(const int* __restrict__ cnt, float* __restrict__ dinv,
               int* __restrict__ bsum, int N) {
    __shared__ int wsum[4];
    int b = blockIdx.x, t = threadIdx.x;
    int i = b * 256 + t;
    int v = (i < N) ? cnt[i] : 0;
    if (i < N) dinv[i] = rsqrtf((float)v + 1.0f);
    int s = v;
#pragma unroll
    for (int d = 1; d < 64; d <<= 1) s += __shfl_xor(s, d, 64);
    if ((t & 63) == 0) wsum[t >> 6] = s;
    __syncthreads();
    if (t == 0) bsum[b] = wsum[0] + wsum[1] + wsum[2] + wsum[3];
}

__global__ __launch_bounds__(256)
void k_scan_bsum(const int* __restrict__ bsum, int* __restrict__ boff, int NB) {
    __shared__ int wsum[4];
    int t = threadIdx.x;
    int v = (t < NB) ? bsum[t] : 0;
    int lane = t & 63, w = t >> 6;
    int sv = v;
#pragma unroll
    for (int d = 1; d < 64; d <<= 1) {
        int u = __shfl_up(sv, d, 64);
        if (lane >= d) sv += u;
    }
    if (lane == 63) wsum[w] = sv;
    __syncthreads();
    int add = 0;
    for (int ww = 0; ww < w; ++ww) add += wsum[ww];
    if (t < NB) boff[t] = sv + add - v;
}

__global__ __launch_bounds__(256)
void k_offsets(const int* __restrict__ cnt, const int* __restrict__ boff,
               int* __restrict__ off, int N) {
    __shared__ int wsum[4];
    int b = blockIdx.x, t = threadIdx.x;
    int i = b * 256 + t;
    int v = (i < N) ? cnt[i] : 0;
    int lane = t & 63, w = t >> 6;
    int sv = v;
#pragma unroll
    for (int d = 1; d < 64; d <<= 1) {
        int u = __shfl_up(sv, d, 64);
        if (lane >= d) sv += u;
    }
    if (lane == 63) wsum[w] = sv;
    __syncthreads();
    int add = boff[b];
    for (int ww = 0; ww < w; ++ww) add += wsum[ww];
    if (i < N) off[i + 1] = add + sv;
    if (i == 0) off[0] = 0;
}

__global__ void k_bucket(const int* __restrict__ srcv, const int* __restrict__ dstv,
                         const int* __restrict__ off, int* cnt2, int* csr, int E) {
    int i = blockIdx.x * blockDim.x + threadIdx.x;
    if (i < E) {
        int d = dstv[i];
        int slot = off[d] + atomicAdd(&cnt2[d], 1);
        csr[slot] = srcv[i];
    }
}

// ---------------- weight prep: WT[c][k] split hi/lo bf16 ----------------
__global__ void k_wprep(const float* __restrict__ W1, const float* __restrict__ W2,
                        const float* __restrict__ W3,
                        unsigned short* WT1h, unsigned short* WT1l,
                        unsigned short* WT2h, unsigned short* WT2l,
                        unsigned short* WT3h, unsigned short* WT3l) {
    int t = blockIdx.x * blockDim.x + threadIdx.x;
    if (t >= 16384) return;
    int c = t >> 7, k = t & 127;
    float w = W1[k * 128 + c];
    unsigned short h = f2bf_rne(w);
    WT1h[c * 128 + k] = h; WT1l[c * 128 + k] = f2bf_rne(w - bf2f(h));
    w = W2[k * 128 + c];
    h = f2bf_rne(w);
    WT2h[c * 128 + k] = h; WT2l[c * 128 + k] = f2bf_rne(w - bf2f(h));
    if (c < 64) {
        w = W3[k * 64 + c];
        h = f2bf_rne(w);
        WT3h[c * 128 + k] = h; WT3l[c * 128 + k] = f2bf_rne(w - bf2f(h));
    }
}

// ---------------- x -> hi/lo bf16 ----------------
__global__ void k_xprep(const float* __restrict__ x, unsigned short* __restrict__ Xh,
                        unsigned short* __restrict__ Xl, long n4) {
    long t = (long)blockIdx.x * blockDim.x + threadIdx.x;
    if (t >= n4) return;
    float4 v = *(const float4*)&x[t * 4];
    ushort4 h, lo;
    h.x = f2bf_rne(v.x); lo.x = f2bf_rne(v.x - bf2f(h.x));
    h.y = f2bf_rne(v.y); lo.y = f2bf_rne(v.y - bf2f(h.y));
    h.z = f2bf_rne(v.z); lo.z = f2bf_rne(v.z - bf2f(h.z));
    h.w = f2bf_rne(v.w); lo.w = f2bf_rne(v.w - bf2f(h.w));
    *(ushort4*)&Xh[t * 4] = h;
    *(ushort4*)&Xl[t * 4] = lo;
}

// ---------------- MFMA GEMM: A[r][c] = (X@W)[r][c] * dinv[r] ----------------
// X given as hi/lo bf16 [N][128]; W as WT[col][128] hi/lo bf16.
// Block = 256 thr = 4 waves; wave w computes rows [b*64+w*16, +16) x all M cols.
template<int M>
__global__ __launch_bounds__(256)
void k_gemm_mfma(const unsigned short* __restrict__ Xh, const unsigned short* __restrict__ Xl,
                 const unsigned short* __restrict__ WTh, const unsigned short* __restrict__ WTl,
                 const float* __restrict__ dinv, float* __restrict__ A, int N) {
    constexpr int NCB = M / 16;
    int wv = threadIdx.x >> 6, l = threadIdx.x & 63;
    int r0w = blockIdx.x * 64 + wv * 16;
    int arow = r0w + (l & 15);
    if (arow >= N) arow = N - 1;
    int kb = (l >> 4) * 8;

    bf16x8 ah[4], al[4];
#pragma unroll
    for (int ks = 0; ks < 4; ++ks) {
        ah[ks] = *(const bf16x8*)&Xh[(long)arow * 128 + ks * 32 + kb];
        al[ks] = *(const bf16x8*)&Xl[(long)arow * 128 + ks * 32 + kb];
    }

    f32x4 acc[NCB];
#pragma unroll
    for (int cb = 0; cb < NCB; ++cb) acc[cb] = f32x4{0.f, 0.f, 0.f, 0.f};

#pragma unroll
    for (int ks = 0; ks < 4; ++ks) {
#pragma unroll
        for (int cb = 0; cb < NCB; ++cb) {
            const unsigned short* wh = &WTh[(long)(cb * 16 + (l & 15)) * 128 + ks * 32 + kb];
            const unsigned short* wl = &WTl[(long)(cb * 16 + (l & 15)) * 128 + ks * 32 + kb];
            bf16x8 bh = *(const bf16x8*)wh;
            bf16x8 bl = *(const bf16x8*)wl;
            acc[cb] = __builtin_amdgcn_mfma_f32_16x16x32_bf16(ah[ks], bh, acc[cb], 0, 0, 0);
            acc[cb] = __builtin_amdgcn_mfma_f32_16x16x32_bf16(ah[ks], bl, acc[cb], 0, 0, 0);
            acc[cb] = __builtin_amdgcn_mfma_f32_16x16x32_bf16(al[ks], bh, acc[cb], 0, 0, 0);
        }
    }

    // C/D layout: col = l&15, row = (l>>4)*4 + i   [verified m89]
    int rbase = r0w + (l >> 4) * 4;
    float dv[4];
#pragma unroll
    for (int i = 0; i < 4; ++i) dv[i] = (rbase + i < N) ? dinv[rbase + i] : 0.f;
#pragma unroll
    for (int cb = 0; cb < NCB; ++cb) {
#pragma unroll
        for (int i = 0; i < 4; ++i) {
            int r = rbase + i;
            if (r < N) A[(long)r * M + cb * 16 + (l & 15)] = acc[cb][i] * dv[i];
        }
    }
}

// ---------------- fused gather + finish ----------------
// mode 0: write fp32 Bf;  mode 1: write hi/lo bf16 (Bh, Bl)
__global__ void k_gather(const float* __restrict__ A, const int* __restrict__ off,
                         const int* __restrict__ csr, const float* __restrict__ dinv,
                         const float* __restrict__ bias, float* __restrict__ Bf,
                         unsigned short* __restrict__ Bh, unsigned short* __restrict__ Bl,
                         int N, int M, int lg, int relu, int mode) {
    int t = blockIdx.x * blockDim.x + threadIdx.x;
    int node = t >> lg;
    if (node >= N) return;
    int q = (t & ((1 << lg) - 1)) << 2;
    const float* Aq = A + q;

    float4 acc = *(const float4*)&Aq[(long)node * M];  // self-loop
    float4 acc1 = make_float4(0.f, 0.f, 0.f, 0.f);
    int j = off[node], j1 = off[node + 1];
    for (; j + 8 <= j1; j += 8) {
        int s0 = csr[j + 0], s1 = csr[j + 1], s2 = csr[j + 2], s3 = csr[j + 3];
        int s4 = csr[j + 4], s5 = csr[j + 5], s6 = csr[j + 6], s7 = csr[j + 7];
        float4 v0 = *(const float4*)&Aq[(long)s0 * M];
        float4 v1 = *(const float4*)&Aq[(long)s1 * M];
        float4 v2 = *(const float4*)&Aq[(long)s2 * M];
        float4 v3 = *(const float4*)&Aq[(long)s3 * M];
        float4 v4 = *(const float4*)&Aq[(long)s4 * M];
        float4 v5 = *(const float4*)&Aq[(long)s5 * M];
        float4 v6 = *(const float4*)&Aq[(long)s6 * M];
        float4 v7 = *(const float4*)&Aq[(long)s7 * M];
        acc.x += v0.x + v1.x + v2.x + v3.x;
        acc.y += v0.y + v1.y + v2.y + v3.y;
        acc.z += v0.z + v1.z + v2.z + v3.z;
        acc.w += v0.w + v1.w + v2.w + v3.w;
        acc1.x += v4.x + v5.x + v6.x + v7.x;
        acc1.y += v4.y + v5.y + v6.y + v7.y;
        acc1.z += v4.z + v5.z + v6.z + v7.z;
        acc1.w += v4.w + v5.w + v6.w + v7.w;
    }
    for (; j + 2 <= j1; j += 2) {
        int s0 = csr[j + 0], s1 = csr[j + 1];
        float4 v0 = *(const float4*)&Aq[(long)s0 * M];
        float4 v1 = *(const float4*)&Aq[(long)s1 * M];
        acc.x += v0.x + v1.x; acc.y += v0.y + v1.y;
        acc.z += v0.z + v1.z; acc.w += v0.w + v1.w;
    }
    if (j < j1) {
        int s = csr[j];
        float4 v = *(const float4*)&Aq[(long)s * M];
        acc.x += v.x; acc.y += v.y; acc.z += v.z; acc.w += v.w;
    }
    acc.x += acc1.x; acc.y += acc1.y; acc.z += acc1.z; acc.w += acc1.w;

    float sc = dinv[node];
    float4 bb = *(const float4*)&bias[q];
    acc.x = acc.x * sc + bb.x;
    acc.y = acc.y * sc + bb.y;
    acc.z = acc.z * sc + bb.z;
    acc.w = acc.w * sc + bb.w;
    if (relu) {
        acc.x = fmaxf(acc.x, 0.f); acc.y = fmaxf(acc.y, 0.f);
        acc.z = fmaxf(acc.z, 0.f); acc.w = fmaxf(acc.w, 0.f);
    }
    if (mode == 0) {
        *(float4*)&Bf[(long)node * M + q] = acc;
    } else {
        ushort4 h, lo;
        h.x = f2bf_rne(acc.x); lo.x = f2bf_rne(acc.x - bf2f(h.x));
        h.y = f2bf_rne(acc.y); lo.y = f2bf_rne(acc.y - bf2f(h.y));
        h.z = f2bf_rne(acc.z); lo.z = f2bf_rne(acc.z - bf2f(h.z));
        h.w = f2bf_rne(acc.w); lo.w = f2bf_rne(acc.w - bf2f(h.w));
        *(ushort4*)&Bh[(long)node * M + q] = h;
        *(ushort4*)&Bl[(long)node * M + q] = lo;
    }
}

// ---------------- decode: out[i] = dot64(z[a], z[b]) ----------------
__global__ void k_decode(const float* __restrict__ z, const int* __restrict__ eli,
                         float* __restrict__ out, int L) {
    int t = blockIdx.x * blockDim.x + threadIdx.x;
    int e = t >> 4;
    int lane = t & 15;
    if (e >= L) return;
    int a = eli[e], b = eli[L + e];
    float4 va = *(const float4*)&z[(long)a * 64 + lane * 4];
    float4 vb = *(const float4*)&z[(long)b * 64 + lane * 4];
    float s = va.x * vb.x + va.y * vb.y + va.z * vb.z + va.w * vb.w;
    s += __shfl_xor(s, 1, 16);
    s += __shfl_xor(s, 2, 16);
    s += __shfl_xor(s, 4, 16);
    s += __shfl_xor(s, 8, 16);
    if (lane == 0) out[e] = s;
}

extern "C" void kernel_launch(void* const* d_in, const int* in_sizes, int n_in,
                              void* d_out, int out_size, void* d_ws, size_t ws_size,
                              hipStream_t stream) {
    const float* x   = (const float*)d_in[0];
    const float* W1  = (const float*)d_in[1];
    const float* b1  = (const float*)d_in[2];
    const float* W2  = (const float*)d_in[3];
    const float* b2  = (const float*)d_in[4];
    const float* W3  = (const float*)d_in[5];
    const float* b3  = (const float*)d_in[6];
    const int*   ei  = (const int*)d_in[7];
    const int*   eli = (const int*)d_in[8];
    float* out = (float*)d_out;

    char* ws = (char*)d_ws;
    float* dinv = (float*)ws;                 ws += 50048 * 4;
    float* A    = (float*)ws;                 ws += (long)N_NODES * 128 * 4;   // also: A64 | z
    unsigned short* inh = (unsigned short*)ws; ws += (long)N_NODES * 128 * 2;
    unsigned short* inl = (unsigned short*)ws; ws += (long)N_NODES * 128 * 2;
    int*   cnt  = (int*)ws;                   ws += 50048 * 4;
    int*   cnt2 = (int*)ws;                   ws += 50048 * 4;
    int*   off  = (int*)ws;                   ws += 50048 * 4;
    int*   csr  = (int*)ws;                   ws += (long)N_EDGES * 4;
    int*   bsum = (int*)ws;                   ws += 256 * 4;
    int*   boff = (int*)ws;                   ws += 256 * 4;
    unsigned short* WT1h = (unsigned short*)ws; ws += 16384 * 2;
    unsigned short* WT1l = (unsigned short*)ws; ws += 16384 * 2;
    unsigned short* WT2h = (unsigned short*)ws; ws += 16384 * 2;
    unsigned short* WT2l = (unsigned short*)ws; ws += 16384 * 2;
    unsigned short* WT3h = (unsigned short*)ws; ws += 8192 * 2;
    unsigned short* WT3l = (unsigned short*)ws; ws += 8192 * 2;

    float* z = A + (long)N_NODES * 64;   // second half of A buffer (layer-3 A uses first half)

    const int* esrc = ei;
    const int* edst = ei + N_EDGES;

    const int NB = (N_NODES + 255) / 256;  // 196

    // CSR build + dinv
    k_zero2    <<<NB, 256, 0, stream>>>(cnt, cnt2, N_NODES);
    k_deg_count<<<(N_EDGES + 255) / 256, 256, 0, stream>>>(edst, cnt, N_EDGES);
    k_partial  <<<NB, 256, 0, stream>>>(cnt, dinv, bsum, N_NODES);
    k_scan_bsum<<<1, 256, 0, stream>>>(bsum, boff, NB);
    k_offsets  <<<NB, 256, 0, stream>>>(cnt, boff, off, N_NODES);
    k_bucket   <<<(N_EDGES + 255) / 256, 256, 0, stream>>>(esrc, edst, off, cnt2, csr, N_EDGES);

    // weight + input prep
    k_wprep<<<64, 256, 0, stream>>>(W1, W2, W3, WT1h, WT1l, WT2h, WT2l, WT3h, WT3l);
    const long n4 = (long)N_NODES * 128 / 4;
    k_xprep<<<(int)((n4 + 255) / 256), 256, 0, stream>>>(x, inh, inl, n4);

    const int gemm_grid = (N_NODES + 63) / 64;
    const int ga128 = (N_NODES * 32 + 255) / 256;
    const int ga64  = (N_NODES * 16 + 255) / 256;

    // layer 1
    k_gemm_mfma<128><<<gemm_grid, 256, 0, stream>>>(inh, inl, WT1h, WT1l, dinv, A, N_NODES);
    k_gather<<<ga128, 256, 0, stream>>>(A, off, csr, dinv, b1, nullptr, inh, inl,
                                        N_NODES, 128, 5, 1, 1);
    // layer 2
    k_gemm_mfma<128><<<gemm_grid, 256, 0, stream>>>(inh, inl, WT2h, WT2l, dinv, A, N_NODES);
    k_gather<<<ga128, 256, 0, stream>>>(A, off, csr, dinv, b2, nullptr, inh, inl,
                                        N_NODES, 128, 5, 1, 1);
    // layer 3 (M=64, no relu, fp32 out)
    k_gemm_mfma<64><<<gemm_grid, 256, 0, stream>>>(inh, inl, WT3h, WT3l, dinv, A, N_NODES);
    k_gather<<<ga64, 256, 0, stream>>>(A, off, csr, dinv, b3, z, nullptr, nullptr,
                                       N_NODES, 64, 4, 0, 0);

    // decode
    k_decode<<<(N_LABEL * 16 + 255) / 256, 256, 0, stream>>>(z, eli, out, N_LABEL);
}

// Round 5
// 297.569 us; speedup vs baseline: 1.2152x; 1.2152x over previous
//
#include <hip/hip_runtime.h>

#define N_NODES 50000
#define N_EDGES 800000
#define N_LABEL 200000

typedef __attribute__((ext_vector_type(8))) short bf16x8;
typedef __attribute__((ext_vector_type(4))) float f32x4;
typedef _Float16 f16;
typedef __attribute__((ext_vector_type(8))) _Float16 f16x8;
typedef __attribute__((ext_vector_type(8))) unsigned short u16x8;

__device__ inline unsigned short f2bf_rne(float f) {
    union { float f; unsigned u; } v; v.f = f;
    unsigned r = v.u + 0x7fffu + ((v.u >> 16) & 1u);
    return (unsigned short)(r >> 16);
}
__device__ inline float bf2f(unsigned short h) {
    union { unsigned u; float f; } v; v.u = ((unsigned)h) << 16;
    return v.f;
}

// ---------------- fused prep: zero cnt/cnt2 + x->hi/lo bf16 + W transpose/split ----------------
// blocks [0,6250): xprep; [6250,6314): wprep; [6314,6510): zero
__global__ __launch_bounds__(256)
void k_prep(const float* __restrict__ x, unsigned short* __restrict__ Xh,
            unsigned short* __restrict__ Xl,
            const float* __restrict__ W1, const float* __restrict__ W2,
            const float* __restrict__ W3,
            unsigned short* WT1h, unsigned short* WT1l,
            unsigned short* WT2h, unsigned short* WT2l,
            unsigned short* WT3h, unsigned short* WT3l,
            int* cnt, int* cnt2) {
    int b = blockIdx.x, tid = threadIdx.x;
    if (b < 6250) {
        long t = (long)b * 256 + tid;          // < 1,600,000 exactly
        float4 v = *(const float4*)&x[t * 4];
        ushort4 h, lo;
        h.x = f2bf_rne(v.x); lo.x = f2bf_rne(v.x - bf2f(h.x));
        h.y = f2bf_rne(v.y); lo.y = f2bf_rne(v.y - bf2f(h.y));
        h.z = f2bf_rne(v.z); lo.z = f2bf_rne(v.z - bf2f(h.z));
        h.w = f2bf_rne(v.w); lo.w = f2bf_rne(v.w - bf2f(h.w));
        *(ushort4*)&Xh[t * 4] = h;
        *(ushort4*)&Xl[t * 4] = lo;
    } else if (b < 6314) {
        int t = (b - 6250) * 256 + tid;        // < 16384
        int c = t >> 7, k = t & 127;
        float w = W1[k * 128 + c];
        unsigned short h = f2bf_rne(w);
        WT1h[c * 128 + k] = h; WT1l[c * 128 + k] = f2bf_rne(w - bf2f(h));
        w = W2[k * 128 + c];
        h = f2bf_rne(w);
        WT2h[c * 128 + k] = h; WT2l[c * 128 + k] = f2bf_rne(w - bf2f(h));
        if (c < 64) {
            w = W3[k * 64 + c];
            h = f2bf_rne(w);
            WT3h[c * 128 + k] = h; WT3l[c * 128 + k] = f2bf_rne(w - bf2f(h));
        }
    } else {
        int i = (b - 6314) * 256 + tid;
        if (i < N_NODES) { cnt[i] = 0; cnt2[i] = 0; }
    }
}

// ---------------- CSR build ----------------
__global__ void k_deg_count(const int* __restrict__ dst, int* cnt, int E) {
    int i = blockIdx.x * blockDim.x + threadIdx.x;
    if (i < E) atomicAdd(&cnt[dst[i]], 1);
}

__global__ __launch_bounds__(256)
void k_partial(const int* __restrict__ cnt, float* __restrict__ dinv,
               int* __restrict__ bsum, int N) {
    __shared__ int wsum[4];
    int b = blockIdx.x, t = threadIdx.x;
    int i = b * 256 + t;
    int v = (i < N) ? cnt[i] : 0;
    if (i < N) dinv[i] = rsqrtf((float)v + 1.0f);
    int s = v;
#pragma unroll
    for (int d = 1; d < 64; d <<= 1) s += __shfl_xor(s, d, 64);
    if ((t & 63) == 0) wsum[t >> 6] = s;
    __syncthreads();
    if (t == 0) bsum[b] = wsum[0] + wsum[1] + wsum[2] + wsum[3];
}

__global__ __launch_bounds__(256)
void k_scan_bsum(const int* __restrict__ bsum, int* __restrict__ boff, int NB) {
    __shared__ int wsum[4];
    int t = threadIdx.x;
    int v = (t < NB) ? bsum[t] : 0;
    int lane = t & 63, w = t >> 6;
    int sv = v;
#pragma unroll
    for (int d = 1; d < 64; d <<= 1) {
        int u = __shfl_up(sv, d, 64);
        if (lane >= d) sv += u;
    }
    if (lane == 63) wsum[w] = sv;
    __syncthreads();
    int add = 0;
    for (int ww = 0; ww < w; ++ww) add += wsum[ww];
    if (t < NB) boff[t] = sv + add - v;
}

__global__ __launch_bounds__(256)
void k_offsets(const int* __restrict__ cnt, const int* __restrict__ boff,
               int* __restrict__ off, int N) {
    __shared__ int wsum[4];
    int b = blockIdx.x, t = threadIdx.x;
    int i = b * 256 + t;
    int v = (i < N) ? cnt[i] : 0;
    int lane = t & 63, w = t >> 6;
    int sv = v;
#pragma unroll
    for (int d = 1; d < 64; d <<= 1) {
        int u = __shfl_up(sv, d, 64);
        if (lane >= d) sv += u;
    }
    if (lane == 63) wsum[w] = sv;
    __syncthreads();
    int add = boff[b];
    for (int ww = 0; ww < w; ++ww) add += wsum[ww];
    if (i < N) off[i + 1] = add + sv;
    if (i == 0) off[0] = 0;
}

__global__ void k_bucket(const int* __restrict__ srcv, const int* __restrict__ dstv,
                         const int* __restrict__ off, int* cnt2, int* csr, int E) {
    int i = blockIdx.x * blockDim.x + threadIdx.x;
    if (i < E) {
        int d = dstv[i];
        int slot = off[d] + atomicAdd(&cnt2[d], 1);
        csr[slot] = srcv[i];
    }
}

// ---------------- MFMA GEMM: A[r][c] = fp16((X@W)[r][c] * dinv[r]) ----------------
template<int M>
__global__ __launch_bounds__(256)
void k_gemm_mfma(const unsigned short* __restrict__ Xh, const unsigned short* __restrict__ Xl,
                 const unsigned short* __restrict__ WTh, const unsigned short* __restrict__ WTl,
                 const float* __restrict__ dinv, f16* __restrict__ A, int N) {
    constexpr int NCB = M / 16;
    int wv = threadIdx.x >> 6, l = threadIdx.x & 63;
    int r0w = blockIdx.x * 64 + wv * 16;
    int arow = r0w + (l & 15);
    if (arow >= N) arow = N - 1;
    int kb = (l >> 4) * 8;

    bf16x8 ah[4], al[4];
#pragma unroll
    for (int ks = 0; ks < 4; ++ks) {
        ah[ks] = *(const bf16x8*)&Xh[(long)arow * 128 + ks * 32 + kb];
        al[ks] = *(const bf16x8*)&Xl[(long)arow * 128 + ks * 32 + kb];
    }

    f32x4 acc[NCB];
#pragma unroll
    for (int cb = 0; cb < NCB; ++cb) acc[cb] = f32x4{0.f, 0.f, 0.f, 0.f};

#pragma unroll
    for (int ks = 0; ks < 4; ++ks) {
#pragma unroll
        for (int cb = 0; cb < NCB; ++cb) {
            const unsigned short* wh = &WTh[(long)(cb * 16 + (l & 15)) * 128 + ks * 32 + kb];
            const unsigned short* wl = &WTl[(long)(cb * 16 + (l & 15)) * 128 + ks * 32 + kb];
            bf16x8 bh = *(const bf16x8*)wh;
            bf16x8 bl = *(const bf16x8*)wl;
            acc[cb] = __builtin_amdgcn_mfma_f32_16x16x32_bf16(ah[ks], bh, acc[cb], 0, 0, 0);
            acc[cb] = __builtin_amdgcn_mfma_f32_16x16x32_bf16(ah[ks], bl, acc[cb], 0, 0, 0);
            acc[cb] = __builtin_amdgcn_mfma_f32_16x16x32_bf16(al[ks], bh, acc[cb], 0, 0, 0);
        }
    }

    // C/D layout: col = l&15, row = (l>>4)*4 + i
    int rbase = r0w + (l >> 4) * 4;
    float dv[4];
#pragma unroll
    for (int i = 0; i < 4; ++i) dv[i] = (rbase + i < N) ? dinv[rbase + i] : 0.f;
#pragma unroll
    for (int cb = 0; cb < NCB; ++cb) {
#pragma unroll
        for (int i = 0; i < 4; ++i) {
            int r = rbase + i;
            if (r < N) A[(long)r * M + cb * 16 + (l & 15)] = (f16)(acc[cb][i] * dv[i]);
        }
    }
}

// ---------------- fused gather + finish (A in fp16, 8 ch/thread) ----------------
// mode 0: write fp32 Bf;  mode 1: write hi/lo bf16 (Bh, Bl)
__global__ __launch_bounds__(256)
void k_gather(const f16* __restrict__ A, const int* __restrict__ off,
              const int* __restrict__ csr, const float* __restrict__ dinv,
              const float* __restrict__ bias, float* __restrict__ Bf,
              unsigned short* __restrict__ Bh, unsigned short* __restrict__ Bl,
              int N, int M, int lg, int relu, int mode) {
    int t = blockIdx.x * blockDim.x + threadIdx.x;
    int node = t >> lg;
    if (node >= N) return;
    int q = (t & ((1 << lg) - 1)) << 3;   // 8 channels per thread
    const f16* Aq = A + q;

    float acc[8];
    {
        f16x8 v = *(const f16x8*)&Aq[(long)node * M];  // self-loop
#pragma unroll
        for (int c = 0; c < 8; ++c) acc[c] = (float)v[c];
    }
    int j = off[node], j1 = off[node + 1];
    for (; j + 8 <= j1; j += 8) {
        int s0 = csr[j + 0], s1 = csr[j + 1], s2 = csr[j + 2], s3 = csr[j + 3];
        int s4 = csr[j + 4], s5 = csr[j + 5], s6 = csr[j + 6], s7 = csr[j + 7];
        f16x8 v0 = *(const f16x8*)&Aq[(long)s0 * M];
        f16x8 v1 = *(const f16x8*)&Aq[(long)s1 * M];
        f16x8 v2 = *(const f16x8*)&Aq[(long)s2 * M];
        f16x8 v3 = *(const f16x8*)&Aq[(long)s3 * M];
        f16x8 v4 = *(const f16x8*)&Aq[(long)s4 * M];
        f16x8 v5 = *(const f16x8*)&Aq[(long)s5 * M];
        f16x8 v6 = *(const f16x8*)&Aq[(long)s6 * M];
        f16x8 v7 = *(const f16x8*)&Aq[(long)s7 * M];
#pragma unroll
        for (int c = 0; c < 8; ++c)
            acc[c] += ((float)v0[c] + (float)v1[c] + (float)v2[c] + (float)v3[c])
                    + ((float)v4[c] + (float)v5[c] + (float)v6[c] + (float)v7[c]);
    }
    for (; j + 2 <= j1; j += 2) {
        int s0 = csr[j + 0], s1 = csr[j + 1];
        f16x8 v0 = *(const f16x8*)&Aq[(long)s0 * M];
        f16x8 v1 = *(const f16x8*)&Aq[(long)s1 * M];
#pragma unroll
        for (int c = 0; c < 8; ++c) acc[c] += (float)v0[c] + (float)v1[c];
    }
    if (j < j1) {
        int s = csr[j];
        f16x8 v = *(const f16x8*)&Aq[(long)s * M];
#pragma unroll
        for (int c = 0; c < 8; ++c) acc[c] += (float)v[c];
    }

    float sc = dinv[node];
    float4 bb0 = *(const float4*)&bias[q];
    float4 bb1 = *(const float4*)&bias[q + 4];
    float bv[8] = {bb0.x, bb0.y, bb0.z, bb0.w, bb1.x, bb1.y, bb1.z, bb1.w};
#pragma unroll
    for (int c = 0; c < 8; ++c) {
        acc[c] = acc[c] * sc + bv[c];
        if (relu) acc[c] = fmaxf(acc[c], 0.f);
    }
    if (mode == 0) {
        float4 o0 = make_float4(acc[0], acc[1], acc[2], acc[3]);
        float4 o1 = make_float4(acc[4], acc[5], acc[6], acc[7]);
        *(float4*)&Bf[(long)node * M + q] = o0;
        *(float4*)&Bf[(long)node * M + q + 4] = o1;
    } else {
        u16x8 h, lo;
#pragma unroll
        for (int c = 0; c < 8; ++c) {
            unsigned short hh = f2bf_rne(acc[c]);
            h[c] = hh;
            lo[c] = f2bf_rne(acc[c] - bf2f(hh));
        }
        *(u16x8*)&Bh[(long)node * M + q] = h;
        *(u16x8*)&Bl[(long)node * M + q] = lo;
    }
}

// ---------------- decode: out[i] = dot64(z[a], z[b]) ----------------
__global__ void k_decode(const float* __restrict__ z, const int* __restrict__ eli,
                         float* __restrict__ out, int L) {
    int t = blockIdx.x * blockDim.x + threadIdx.x;
    int e = t >> 4;
    int lane = t & 15;
    if (e >= L) return;
    int a = eli[e], b = eli[L + e];
    float4 va = *(const float4*)&z[(long)a * 64 + lane * 4];
    float4 vb = *(const float4*)&z[(long)b * 64 + lane * 4];
    float s = va.x * vb.x + va.y * vb.y + va.z * vb.z + va.w * vb.w;
    s += __shfl_xor(s, 1, 16);
    s += __shfl_xor(s, 2, 16);
    s += __shfl_xor(s, 4, 16);
    s += __shfl_xor(s, 8, 16);
    if (lane == 0) out[e] = s;
}

extern "C" void kernel_launch(void* const* d_in, const int* in_sizes, int n_in,
                              void* d_out, int out_size, void* d_ws, size_t ws_size,
                              hipStream_t stream) {
    const float* x   = (const float*)d_in[0];
    const float* W1  = (const float*)d_in[1];
    const float* b1  = (const float*)d_in[2];
    const float* W2  = (const float*)d_in[3];
    const float* b2  = (const float*)d_in[4];
    const float* W3  = (const float*)d_in[5];
    const float* b3  = (const float*)d_in[6];
    const int*   ei  = (const int*)d_in[7];
    const int*   eli = (const int*)d_in[8];
    float* out = (float*)d_out;

    char* ws = (char*)d_ws;
    float* dinv = (float*)ws;                  ws += 50048 * 4;
    f16*   A    = (f16*)ws;                    ws += (long)N_NODES * 128 * 2;
    float* z    = (float*)ws;                  ws += (long)N_NODES * 64 * 4;
    unsigned short* inh = (unsigned short*)ws; ws += (long)N_NODES * 128 * 2;
    unsigned short* inl = (unsigned short*)ws; ws += (long)N_NODES * 128 * 2;
    int*   cnt  = (int*)ws;                    ws += 50048 * 4;
    int*   cnt2 = (int*)ws;                    ws += 50048 * 4;
    int*   off  = (int*)ws;                    ws += 50048 * 4;
    int*   csr  = (int*)ws;                    ws += (long)N_EDGES * 4;
    int*   bsum = (int*)ws;                    ws += 256 * 4;
    int*   boff = (int*)ws;                    ws += 256 * 4;
    unsigned short* WT1h = (unsigned short*)ws; ws += 16384 * 2;
    unsigned short* WT1l = (unsigned short*)ws; ws += 16384 * 2;
    unsigned short* WT2h = (unsigned short*)ws; ws += 16384 * 2;
    unsigned short* WT2l = (unsigned short*)ws; ws += 16384 * 2;
    unsigned short* WT3h = (unsigned short*)ws; ws += 8192 * 2;
    unsigned short* WT3l = (unsigned short*)ws; ws += 8192 * 2;

    const int* esrc = ei;
    const int* edst = ei + N_EDGES;

    const int NB = (N_NODES + 255) / 256;  // 196

    // fused prep (zero + xprep + wprep), then CSR build
    k_prep     <<<6510, 256, 0, stream>>>(x, inh, inl, W1, W2, W3,
                                          WT1h, WT1l, WT2h, WT2l, WT3h, WT3l, cnt, cnt2);
    k_deg_count<<<(N_EDGES + 255) / 256, 256, 0, stream>>>(edst, cnt, N_EDGES);
    k_partial  <<<NB, 256, 0, stream>>>(cnt, dinv, bsum, N_NODES);
    k_scan_bsum<<<1, 256, 0, stream>>>(bsum, boff, NB);
    k_offsets  <<<NB, 256, 0, stream>>>(cnt, boff, off, N_NODES);
    k_bucket   <<<(N_EDGES + 255) / 256, 256, 0, stream>>>(esrc, edst, off, cnt2, csr, N_EDGES);

    const int gemm_grid = (N_NODES + 63) / 64;
    const int ga128 = (N_NODES * 16 + 255) / 256;   // 16 thr/node
    const int ga64  = (N_NODES * 8 + 255) / 256;    // 8 thr/node

    // layer 1
    k_gemm_mfma<128><<<gemm_grid, 256, 0, stream>>>(inh, inl, WT1h, WT1l, dinv, A, N_NODES);
    k_gather<<<ga128, 256, 0, stream>>>(A, off, csr, dinv, b1, nullptr, inh, inl,
                                        N_NODES, 128, 4, 1, 1);
    // layer 2
    k_gemm_mfma<128><<<gemm_grid, 256, 0, stream>>>(inh, inl, WT2h, WT2l, dinv, A, N_NODES);
    k_gather<<<ga128, 256, 0, stream>>>(A, off, csr, dinv, b2, nullptr, inh, inl,
                                        N_NODES, 128, 4, 1, 1);
    // layer 3 (M=64, no relu, fp32 out)
    k_gemm_mfma<64><<<gemm_grid, 256, 0, stream>>>(inh, inl, WT3h, WT3l, dinv, A, N_NODES);
    k_gather<<<ga64, 256, 0, stream>>>(A, off, csr, dinv, b3, z, nullptr, nullptr,
                                       N_NODES, 64, 3, 0, 0);

    // decode
    k_decode<<<(N_LABEL * 16 + 255) / 256, 256, 0, stream>>>(z, eli, out, N_LABEL);
}

// Round 6
// 294.803 us; speedup vs baseline: 1.2266x; 1.0094x over previous
//
#include <hip/hip_runtime.h>

#define N_NODES 50000
#define N_EDGES 800000
#define N_LABEL 200000
#define GEMM_BLOCKS 782   // ceil(50000/64)
#define EDGE_BLOCKS 3125  // 800000/256 exactly

typedef __attribute__((ext_vector_type(8))) short bf16x8;
typedef __attribute__((ext_vector_type(4))) float f32x4;
typedef _Float16 f16;
typedef __attribute__((ext_vector_type(8))) _Float16 f16x8;
typedef __attribute__((ext_vector_type(8))) unsigned short u16x8;

__device__ inline unsigned short f2bf_rne(float f) {
    union { float f; unsigned u; } v; v.f = f;
    unsigned r = v.u + 0x7fffu + ((v.u >> 16) & 1u);
    return (unsigned short)(r >> 16);
}
__device__ inline float bf2f(unsigned short h) {
    union { unsigned u; float f; } v; v.u = ((unsigned)h) << 16;
    return v.f;
}

// ---------------- fused prep: x->hi/lo bf16 + W transpose/split + deg_count ----------------
// blocks [0,6250): xprep; [6250,6314): wprep; [6314,9439): deg_count (cnt pre-zeroed by memset)
__global__ __launch_bounds__(256)
void k_prep(const float* __restrict__ x, unsigned short* __restrict__ Xh,
            unsigned short* __restrict__ Xl,
            const float* __restrict__ W1, const float* __restrict__ W2,
            const float* __restrict__ W3,
            unsigned short* WT1h, unsigned short* WT1l,
            unsigned short* WT2h, unsigned short* WT2l,
            unsigned short* WT3h, unsigned short* WT3l,
            const int* __restrict__ dst, int* cnt) {
    int b = blockIdx.x, tid = threadIdx.x;
    if (b < 6250) {
        long t = (long)b * 256 + tid;          // < 1,600,000 exactly
        float4 v = *(const float4*)&x[t * 4];
        ushort4 h, lo;
        h.x = f2bf_rne(v.x); lo.x = f2bf_rne(v.x - bf2f(h.x));
        h.y = f2bf_rne(v.y); lo.y = f2bf_rne(v.y - bf2f(h.y));
        h.z = f2bf_rne(v.z); lo.z = f2bf_rne(v.z - bf2f(h.z));
        h.w = f2bf_rne(v.w); lo.w = f2bf_rne(v.w - bf2f(h.w));
        *(ushort4*)&Xh[t * 4] = h;
        *(ushort4*)&Xl[t * 4] = lo;
    } else if (b < 6314) {
        int t = (b - 6250) * 256 + tid;        // < 16384
        int c = t >> 7, k = t & 127;
        float w = W1[k * 128 + c];
        unsigned short h = f2bf_rne(w);
        WT1h[c * 128 + k] = h; WT1l[c * 128 + k] = f2bf_rne(w - bf2f(h));
        w = W2[k * 128 + c];
        h = f2bf_rne(w);
        WT2h[c * 128 + k] = h; WT2l[c * 128 + k] = f2bf_rne(w - bf2f(h));
        if (c < 64) {
            w = W3[k * 64 + c];
            h = f2bf_rne(w);
            WT3h[c * 128 + k] = h; WT3l[c * 128 + k] = f2bf_rne(w - bf2f(h));
        }
    } else {
        int i = (b - 6314) * 256 + tid;        // < 800,000 exactly
        atomicAdd(&cnt[dst[i]], 1);
    }
}

// ---------------- scan chain ----------------
__global__ __launch_bounds__(256)
void k_partial(const int* __restrict__ cnt, float* __restrict__ dinv,
               int* __restrict__ bsum, int N) {
    __shared__ int wsum[4];
    int b = blockIdx.x, t = threadIdx.x;
    int i = b * 256 + t;
    int v = (i < N) ? cnt[i] : 0;
    if (i < N) dinv[i] = rsqrtf((float)v + 1.0f);
    int s = v;
#pragma unroll
    for (int d = 1; d < 64; d <<= 1) s += __shfl_xor(s, d, 64);
    if ((t & 63) == 0) wsum[t >> 6] = s;
    __syncthreads();
    if (t == 0) bsum[b] = wsum[0] + wsum[1] + wsum[2] + wsum[3];
}

__global__ __launch_bounds__(256)
void k_scan_bsum(const int* __restrict__ bsum, int* __restrict__ boff, int NB) {
    __shared__ int wsum[4];
    int t = threadIdx.x;
    int v = (t < NB) ? bsum[t] : 0;
    int lane = t & 63, w = t >> 6;
    int sv = v;
#pragma unroll
    for (int d = 1; d < 64; d <<= 1) {
        int u = __shfl_up(sv, d, 64);
        if (lane >= d) sv += u;
    }
    if (lane == 63) wsum[w] = sv;
    __syncthreads();
    int add = 0;
    for (int ww = 0; ww < w; ++ww) add += wsum[ww];
    if (t < NB) boff[t] = sv + add - v;
}

__global__ __launch_bounds__(256)
void k_offsets(const int* __restrict__ cnt, const int* __restrict__ boff,
               int* __restrict__ off, int N) {
    __shared__ int wsum[4];
    int b = blockIdx.x, t = threadIdx.x;
    int i = b * 256 + t;
    int v = (i < N) ? cnt[i] : 0;
    int lane = t & 63, w = t >> 6;
    int sv = v;
#pragma unroll
    for (int d = 1; d < 64; d <<= 1) {
        int u = __shfl_up(sv, d, 64);
        if (lane >= d) sv += u;
    }
    if (lane == 63) wsum[w] = sv;
    __syncthreads();
    int add = boff[b];
    for (int ww = 0; ww < w; ++ww) add += wsum[ww];
    if (i < N) off[i + 1] = add + sv;
    if (i == 0) off[0] = 0;
}

// ---------------- fused GEMM1 + bucket-fill ----------------
// blocks [0, GEMM_BLOCKS): A1[r][c] = fp16((X@W1)[r][c] * dinv[r])
// blocks [GEMM_BLOCKS, +EDGE_BLOCKS): csr bucket fill
__global__ __launch_bounds__(256)
void k_gemm1_bucket(const unsigned short* __restrict__ Xh, const unsigned short* __restrict__ Xl,
                    const unsigned short* __restrict__ WTh, const unsigned short* __restrict__ WTl,
                    const float* __restrict__ dinv, f16* __restrict__ A,
                    const int* __restrict__ srcv, const int* __restrict__ dstv,
                    const int* __restrict__ off, int* cnt2, int* csr) {
    int b = blockIdx.x;
    if (b >= GEMM_BLOCKS) {
        int i = (b - GEMM_BLOCKS) * 256 + threadIdx.x;   // < 800,000 exactly
        int d = dstv[i];
        int slot = off[d] + atomicAdd(&cnt2[d], 1);
        csr[slot] = srcv[i];
        return;
    }
    constexpr int M = 128, NCB = 8;
    int wv = threadIdx.x >> 6, l = threadIdx.x & 63;
    int r0w = b * 64 + wv * 16;
    int arow = r0w + (l & 15);
    if (arow >= N_NODES) arow = N_NODES - 1;
    int kb = (l >> 4) * 8;

    bf16x8 ah[4], al[4];
#pragma unroll
    for (int ks = 0; ks < 4; ++ks) {
        ah[ks] = *(const bf16x8*)&Xh[(long)arow * 128 + ks * 32 + kb];
        al[ks] = *(const bf16x8*)&Xl[(long)arow * 128 + ks * 32 + kb];
    }
    f32x4 acc[NCB];
#pragma unroll
    for (int cb = 0; cb < NCB; ++cb) acc[cb] = f32x4{0.f, 0.f, 0.f, 0.f};
#pragma unroll
    for (int ks = 0; ks < 4; ++ks) {
#pragma unroll
        for (int cb = 0; cb < NCB; ++cb) {
            bf16x8 bh = *(const bf16x8*)&WTh[(long)(cb * 16 + (l & 15)) * 128 + ks * 32 + kb];
            bf16x8 bl = *(const bf16x8*)&WTl[(long)(cb * 16 + (l & 15)) * 128 + ks * 32 + kb];
            acc[cb] = __builtin_amdgcn_mfma_f32_16x16x32_bf16(ah[ks], bh, acc[cb], 0, 0, 0);
            acc[cb] = __builtin_amdgcn_mfma_f32_16x16x32_bf16(ah[ks], bl, acc[cb], 0, 0, 0);
            acc[cb] = __builtin_amdgcn_mfma_f32_16x16x32_bf16(al[ks], bh, acc[cb], 0, 0, 0);
        }
    }
    int rbase = r0w + (l >> 4) * 4;
    float dv[4];
#pragma unroll
    for (int i = 0; i < 4; ++i) dv[i] = (rbase + i < N_NODES) ? dinv[rbase + i] : 0.f;
#pragma unroll
    for (int cb = 0; cb < NCB; ++cb) {
#pragma unroll
        for (int i = 0; i < 4; ++i) {
            int r = rbase + i;
            if (r < N_NODES) A[(long)r * M + cb * 16 + (l & 15)] = (f16)(acc[cb][i] * dv[i]);
        }
    }
}

// ---------------- fused gather_i + GEMM_{i+1} ----------------
// phase 1: 64 nodes/block, gather(Ain fp16, 128ch) -> relu(dinv*agg + bias) -> LDS hi/lo bf16
// phase 2: MFMA GEMM from LDS vs WT -> Aout[r][c] = fp16((B@W)[r][c] * dinv[r])
// LDS row stride 136 shorts (272B): lanes alias banks only 2-way (free).
template<int MOUT>
__global__ __launch_bounds__(256)
void k_fused(const f16* __restrict__ Ain, const int* __restrict__ off,
             const int* __restrict__ csr, const float* __restrict__ dinv,
             const float* __restrict__ bias,
             const unsigned short* __restrict__ WTh, const unsigned short* __restrict__ WTl,
             f16* __restrict__ Aout, int N) {
    __shared__ unsigned short Hs[64 * 136];
    __shared__ unsigned short Ls[64 * 136];
    int r0 = blockIdx.x * 64;
    int t = threadIdx.x;
    int q = (t & 15) << 3;              // 8 channels / thread
    const f16* Aq = Ain + q;

    float4 bb0 = *(const float4*)&bias[q];
    float4 bb1 = *(const float4*)&bias[q + 4];
    float bv[8] = {bb0.x, bb0.y, bb0.z, bb0.w, bb1.x, bb1.y, bb1.z, bb1.w};

#pragma unroll
    for (int it = 0; it < 4; ++it) {
        int ln = it * 16 + (t >> 4);    // local node 0..63
        int node = r0 + ln;
        float acc[8] = {0.f, 0.f, 0.f, 0.f, 0.f, 0.f, 0.f, 0.f};
        if (node < N) {
            f16x8 v = *(const f16x8*)&Aq[(long)node * 128];   // self-loop
#pragma unroll
            for (int c = 0; c < 8; ++c) acc[c] = (float)v[c];
            int j = off[node], j1 = off[node + 1];
            for (; j + 8 <= j1; j += 8) {
                int s0 = csr[j + 0], s1 = csr[j + 1], s2 = csr[j + 2], s3 = csr[j + 3];
                int s4 = csr[j + 4], s5 = csr[j + 5], s6 = csr[j + 6], s7 = csr[j + 7];
                f16x8 v0 = *(const f16x8*)&Aq[(long)s0 * 128];
                f16x8 v1 = *(const f16x8*)&Aq[(long)s1 * 128];
                f16x8 v2 = *(const f16x8*)&Aq[(long)s2 * 128];
                f16x8 v3 = *(const f16x8*)&Aq[(long)s3 * 128];
                f16x8 v4 = *(const f16x8*)&Aq[(long)s4 * 128];
                f16x8 v5 = *(const f16x8*)&Aq[(long)s5 * 128];
                f16x8 v6 = *(const f16x8*)&Aq[(long)s6 * 128];
                f16x8 v7 = *(const f16x8*)&Aq[(long)s7 * 128];
#pragma unroll
                for (int c = 0; c < 8; ++c)
                    acc[c] += ((float)v0[c] + (float)v1[c] + (float)v2[c] + (float)v3[c])
                            + ((float)v4[c] + (float)v5[c] + (float)v6[c] + (float)v7[c]);
            }
            for (; j + 2 <= j1; j += 2) {
                int s0 = csr[j + 0], s1 = csr[j + 1];
                f16x8 v0 = *(const f16x8*)&Aq[(long)s0 * 128];
                f16x8 v1 = *(const f16x8*)&Aq[(long)s1 * 128];
#pragma unroll
                for (int c = 0; c < 8; ++c) acc[c] += (float)v0[c] + (float)v1[c];
            }
            if (j < j1) {
                int s = csr[j];
                f16x8 vv = *(const f16x8*)&Aq[(long)s * 128];
#pragma unroll
                for (int c = 0; c < 8; ++c) acc[c] += (float)vv[c];
            }
            float sc = dinv[node];
#pragma unroll
            for (int c = 0; c < 8; ++c) acc[c] = fmaxf(acc[c] * sc + bv[c], 0.f);
        }
        u16x8 h, lo;
#pragma unroll
        for (int c = 0; c < 8; ++c) {
            unsigned short hh = f2bf_rne(acc[c]);
            h[c] = hh;
            lo[c] = f2bf_rne(acc[c] - bf2f(hh));
        }
        *(u16x8*)&Hs[ln * 136 + q] = h;
        *(u16x8*)&Ls[ln * 136 + q] = lo;
    }
    __syncthreads();

    // phase 2: GEMM from LDS
    constexpr int NCB = MOUT / 16;
    int wv = t >> 6, l = t & 63;
    int lrow = wv * 16 + (l & 15);
    int kb = (l >> 4) * 8;
    bf16x8 ah[4], al[4];
#pragma unroll
    for (int ks = 0; ks < 4; ++ks) {
        ah[ks] = *(const bf16x8*)&Hs[lrow * 136 + ks * 32 + kb];
        al[ks] = *(const bf16x8*)&Ls[lrow * 136 + ks * 32 + kb];
    }
    f32x4 acc2[NCB];
#pragma unroll
    for (int cb = 0; cb < NCB; ++cb) acc2[cb] = f32x4{0.f, 0.f, 0.f, 0.f};
#pragma unroll
    for (int ks = 0; ks < 4; ++ks) {
#pragma unroll
        for (int cb = 0; cb < NCB; ++cb) {
            bf16x8 bh = *(const bf16x8*)&WTh[(long)(cb * 16 + (l & 15)) * 128 + ks * 32 + kb];
            bf16x8 bl = *(const bf16x8*)&WTl[(long)(cb * 16 + (l & 15)) * 128 + ks * 32 + kb];
            acc2[cb] = __builtin_amdgcn_mfma_f32_16x16x32_bf16(ah[ks], bh, acc2[cb], 0, 0, 0);
            acc2[cb] = __builtin_amdgcn_mfma_f32_16x16x32_bf16(ah[ks], bl, acc2[cb], 0, 0, 0);
            acc2[cb] = __builtin_amdgcn_mfma_f32_16x16x32_bf16(al[ks], bh, acc2[cb], 0, 0, 0);
        }
    }
    int rbase = r0 + wv * 16 + (l >> 4) * 4;
    float dv[4];
#pragma unroll
    for (int i = 0; i < 4; ++i) dv[i] = (rbase + i < N) ? dinv[rbase + i] : 0.f;
#pragma unroll
    for (int cb = 0; cb < NCB; ++cb) {
#pragma unroll
        for (int i = 0; i < 4; ++i) {
            int r = rbase + i;
            if (r < N) Aout[(long)r * MOUT + cb * 16 + (l & 15)] = (f16)(acc2[cb][i] * dv[i]);
        }
    }
}

// ---------------- final gather (layer 3): A3 fp16 64ch -> z fp32, no relu ----------------
__global__ __launch_bounds__(256)
void k_gather3(const f16* __restrict__ A, const int* __restrict__ off,
               const int* __restrict__ csr, const float* __restrict__ dinv,
               const float* __restrict__ bias, float* __restrict__ z, int N) {
    int t = blockIdx.x * blockDim.x + threadIdx.x;
    int node = t >> 3;
    if (node >= N) return;
    int q = (t & 7) << 3;
    const f16* Aq = A + q;

    float acc[8];
    {
        f16x8 v = *(const f16x8*)&Aq[(long)node * 64];
#pragma unroll
        for (int c = 0; c < 8; ++c) acc[c] = (float)v[c];
    }
    int j = off[node], j1 = off[node + 1];
    for (; j + 8 <= j1; j += 8) {
        int s0 = csr[j + 0], s1 = csr[j + 1], s2 = csr[j + 2], s3 = csr[j + 3];
        int s4 = csr[j + 4], s5 = csr[j + 5], s6 = csr[j + 6], s7 = csr[j + 7];
        f16x8 v0 = *(const f16x8*)&Aq[(long)s0 * 64];
        f16x8 v1 = *(const f16x8*)&Aq[(long)s1 * 64];
        f16x8 v2 = *(const f16x8*)&Aq[(long)s2 * 64];
        f16x8 v3 = *(const f16x8*)&Aq[(long)s3 * 64];
        f16x8 v4 = *(const f16x8*)&Aq[(long)s4 * 64];
        f16x8 v5 = *(const f16x8*)&Aq[(long)s5 * 64];
        f16x8 v6 = *(const f16x8*)&Aq[(long)s6 * 64];
        f16x8 v7 = *(const f16x8*)&Aq[(long)s7 * 64];
#pragma unroll
        for (int c = 0; c < 8; ++c)
            acc[c] += ((float)v0[c] + (float)v1[c] + (float)v2[c] + (float)v3[c])
                    + ((float)v4[c] + (float)v5[c] + (float)v6[c] + (float)v7[c]);
    }
    for (; j + 2 <= j1; j += 2) {
        int s0 = csr[j + 0], s1 = csr[j + 1];
        f16x8 v0 = *(const f16x8*)&Aq[(long)s0 * 64];
        f16x8 v1 = *(const f16x8*)&Aq[(long)s1 * 64];
#pragma unroll
        for (int c = 0; c < 8; ++c) acc[c] += (float)v0[c] + (float)v1[c];
    }
    if (j < j1) {
        int s = csr[j];
        f16x8 v = *(const f16x8*)&Aq[(long)s * 64];
#pragma unroll
        for (int c = 0; c < 8; ++c) acc[c] += (float)v[c];
    }

    float sc = dinv[node];
    float4 bb0 = *(const float4*)&bias[q];
    float4 bb1 = *(const float4*)&bias[q + 4];
    float bv[8] = {bb0.x, bb0.y, bb0.z, bb0.w, bb1.x, bb1.y, bb1.z, bb1.w};
    float4 o0, o1;
    o0.x = acc[0] * sc + bv[0]; o0.y = acc[1] * sc + bv[1];
    o0.z = acc[2] * sc + bv[2]; o0.w = acc[3] * sc + bv[3];
    o1.x = acc[4] * sc + bv[4]; o1.y = acc[5] * sc + bv[5];
    o1.z = acc[6] * sc + bv[6]; o1.w = acc[7] * sc + bv[7];
    *(float4*)&z[(long)node * 64 + q] = o0;
    *(float4*)&z[(long)node * 64 + q + 4] = o1;
}

// ---------------- decode: out[i] = dot64(z[a], z[b]) ----------------
__global__ void k_decode(const float* __restrict__ z, const int* __restrict__ eli,
                         float* __restrict__ out, int L) {
    int t = blockIdx.x * blockDim.x + threadIdx.x;
    int e = t >> 4;
    int lane = t & 15;
    if (e >= L) return;
    int a = eli[e], b = eli[L + e];
    float4 va = *(const float4*)&z[(long)a * 64 + lane * 4];
    float4 vb = *(const float4*)&z[(long)b * 64 + lane * 4];
    float s = va.x * vb.x + va.y * vb.y + va.z * vb.z + va.w * vb.w;
    s += __shfl_xor(s, 1, 16);
    s += __shfl_xor(s, 2, 16);
    s += __shfl_xor(s, 4, 16);
    s += __shfl_xor(s, 8, 16);
    if (lane == 0) out[e] = s;
}

extern "C" void kernel_launch(void* const* d_in, const int* in_sizes, int n_in,
                              void* d_out, int out_size, void* d_ws, size_t ws_size,
                              hipStream_t stream) {
    const float* x   = (const float*)d_in[0];
    const float* W1  = (const float*)d_in[1];
    const float* b1  = (const float*)d_in[2];
    const float* W2  = (const float*)d_in[3];
    const float* b2  = (const float*)d_in[4];
    const float* W3  = (const float*)d_in[5];
    const float* b3  = (const float*)d_in[6];
    const int*   ei  = (const int*)d_in[7];
    const int*   eli = (const int*)d_in[8];
    float* out = (float*)d_out;

    char* ws = (char*)d_ws;
    float* dinv = (float*)ws;                  ws += 50048 * 4;
    f16*   A1   = (f16*)ws;                    ws += (long)N_NODES * 128 * 2;
    f16*   A2   = (f16*)ws;                    ws += (long)N_NODES * 128 * 2;
    float* z    = (float*)ws;                  ws += (long)N_NODES * 64 * 4;
    unsigned short* inh = (unsigned short*)ws; ws += (long)N_NODES * 128 * 2;
    unsigned short* inl = (unsigned short*)ws; ws += (long)N_NODES * 128 * 2;
    int*   cnt  = (int*)ws;                    ws += 50048 * 4;
    int*   cnt2 = (int*)ws;                    ws += 50048 * 4;   // contiguous with cnt
    int*   off  = (int*)ws;                    ws += 50048 * 4;
    int*   csr  = (int*)ws;                    ws += (long)N_EDGES * 4;
    int*   bsum = (int*)ws;                    ws += 256 * 4;
    int*   boff = (int*)ws;                    ws += 256 * 4;
    unsigned short* WT1h = (unsigned short*)ws; ws += 16384 * 2;
    unsigned short* WT1l = (unsigned short*)ws; ws += 16384 * 2;
    unsigned short* WT2h = (unsigned short*)ws; ws += 16384 * 2;
    unsigned short* WT2l = (unsigned short*)ws; ws += 16384 * 2;
    unsigned short* WT3h = (unsigned short*)ws; ws += 8192 * 2;
    unsigned short* WT3l = (unsigned short*)ws; ws += 8192 * 2;

    const int* esrc = ei;
    const int* edst = ei + N_EDGES;

    const int NB = (N_NODES + 255) / 256;  // 196

    // zero cnt+cnt2 (contiguous), then fused prep (xprep + wprep + deg_count)
    hipMemsetAsync(cnt, 0, 2 * 50048 * sizeof(int), stream);
    k_prep     <<<9439, 256, 0, stream>>>(x, inh, inl, W1, W2, W3,
                                          WT1h, WT1l, WT2h, WT2l, WT3h, WT3l, edst, cnt);
    k_partial  <<<NB, 256, 0, stream>>>(cnt, dinv, bsum, N_NODES);
    k_scan_bsum<<<1, 256, 0, stream>>>(bsum, boff, NB);
    k_offsets  <<<NB, 256, 0, stream>>>(cnt, boff, off, N_NODES);

    // GEMM1 (X@W1 -> A1) concurrent with csr bucket fill
    k_gemm1_bucket<<<GEMM_BLOCKS + EDGE_BLOCKS, 256, 0, stream>>>(
        inh, inl, WT1h, WT1l, dinv, A1, esrc, edst, off, cnt2, csr);

    // fused gather1+GEMM2 and gather2+GEMM3
    k_fused<128><<<GEMM_BLOCKS, 256, 0, stream>>>(A1, off, csr, dinv, b1, WT2h, WT2l, A2, N_NODES);
    k_fused<64> <<<GEMM_BLOCKS, 256, 0, stream>>>(A2, off, csr, dinv, b2, WT3h, WT3l, A1, N_NODES);

    // final gather (layer 3) -> z, then decode
    k_gather3<<<(N_NODES * 8 + 255) / 256, 256, 0, stream>>>(A1, off, csr, dinv, b3, z, N_NODES);
    k_decode <<<(N_LABEL * 16 + 255) / 256, 256, 0, stream>>>(z, eli, out, N_LABEL);
}

// Round 7
// 291.467 us; speedup vs baseline: 1.2407x; 1.0114x over previous
//
#include <hip/hip_runtime.h>

#define N_NODES 50000
#define N_EDGES 800000
#define N_LABEL 200000
#define GEMM_BLOCKS 782   // ceil(50000/64)

typedef __attribute__((ext_vector_type(8))) short bf16x8;
typedef __attribute__((ext_vector_type(4))) float f32x4;
typedef _Float16 f16;
typedef __attribute__((ext_vector_type(8))) _Float16 f16x8;
typedef __attribute__((ext_vector_type(8))) unsigned short u16x8;

__device__ inline unsigned short f2bf_rne(float f) {
    union { float f; unsigned u; } v; v.f = f;
    unsigned r = v.u + 0x7fffu + ((v.u >> 16) & 1u);
    return (unsigned short)(r >> 16);
}
__device__ inline float bf2f(unsigned short h) {
    union { unsigned u; float f; } v; v.u = ((unsigned)h) << 16;
    return v.f;
}

// ---------------- fused prep: x->hi/lo bf16 + W transpose/split + deg_count ----------------
// blocks [0,6250): xprep; [6250,6314): wprep; [6314,9439): deg_count (cnt pre-zeroed by memset)
__global__ __launch_bounds__(256)
void k_prep(const float* __restrict__ x, unsigned short* __restrict__ Xh,
            unsigned short* __restrict__ Xl,
            const float* __restrict__ W1, const float* __restrict__ W2,
            const float* __restrict__ W3,
            unsigned short* WT1h, unsigned short* WT1l,
            unsigned short* WT2h, unsigned short* WT2l,
            unsigned short* WT3h, unsigned short* WT3l,
            const int* __restrict__ dst, int* cnt) {
    int b = blockIdx.x, tid = threadIdx.x;
    if (b < 6250) {
        long t = (long)b * 256 + tid;          // < 1,600,000 exactly
        float4 v = *(const float4*)&x[t * 4];
        ushort4 h, lo;
        h.x = f2bf_rne(v.x); lo.x = f2bf_rne(v.x - bf2f(h.x));
        h.y = f2bf_rne(v.y); lo.y = f2bf_rne(v.y - bf2f(h.y));
        h.z = f2bf_rne(v.z); lo.z = f2bf_rne(v.z - bf2f(h.z));
        h.w = f2bf_rne(v.w); lo.w = f2bf_rne(v.w - bf2f(h.w));
        *(ushort4*)&Xh[t * 4] = h;
        *(ushort4*)&Xl[t * 4] = lo;
    } else if (b < 6314) {
        int t = (b - 6250) * 256 + tid;        // < 16384
        int c = t >> 7, k = t & 127;
        float w = W1[k * 128 + c];
        unsigned short h = f2bf_rne(w);
        WT1h[c * 128 + k] = h; WT1l[c * 128 + k] = f2bf_rne(w - bf2f(h));
        w = W2[k * 128 + c];
        h = f2bf_rne(w);
        WT2h[c * 128 + k] = h; WT2l[c * 128 + k] = f2bf_rne(w - bf2f(h));
        if (c < 64) {
            w = W3[k * 64 + c];
            h = f2bf_rne(w);
            WT3h[c * 128 + k] = h; WT3l[c * 128 + k] = f2bf_rne(w - bf2f(h));
        }
    } else {
        int i = (b - 6314) * 256 + tid;        // < 800,000 exactly
        atomicAdd(&cnt[dst[i]], 1);
    }
}

// ---------------- scan chain ----------------
__global__ __launch_bounds__(256)
void k_partial(const int* __restrict__ cnt, float* __restrict__ dinv,
               int* __restrict__ bsum, int N) {
    __shared__ int wsum[4];
    int b = blockIdx.x, t = threadIdx.x;
    int i = b * 256 + t;
    int v = (i < N) ? cnt[i] : 0;
    if (i < N) dinv[i] = rsqrtf((float)v + 1.0f);
    int s = v;
#pragma unroll
    for (int d = 1; d < 64; d <<= 1) s += __shfl_xor(s, d, 64);
    if ((t & 63) == 0) wsum[t >> 6] = s;
    __syncthreads();
    if (t == 0) bsum[b] = wsum[0] + wsum[1] + wsum[2] + wsum[3];
}

__global__ __launch_bounds__(256)
void k_scan_bsum(const int* __restrict__ bsum, int* __restrict__ boff, int NB) {
    __shared__ int wsum[4];
    int t = threadIdx.x;
    int v = (t < NB) ? bsum[t] : 0;
    int lane = t & 63, w = t >> 6;
    int sv = v;
#pragma unroll
    for (int d = 1; d < 64; d <<= 1) {
        int u = __shfl_up(sv, d, 64);
        if (lane >= d) sv += u;
    }
    if (lane == 63) wsum[w] = sv;
    __syncthreads();
    int add = 0;
    for (int ww = 0; ww < w; ++ww) add += wsum[ww];
    if (t < NB) boff[t] = sv + add - v;
}

__global__ __launch_bounds__(256)
void k_offsets(const int* __restrict__ cnt, const int* __restrict__ boff,
               int* __restrict__ off, int N) {
    __shared__ int wsum[4];
    int b = blockIdx.x, t = threadIdx.x;
    int i = b * 256 + t;
    int v = (i < N) ? cnt[i] : 0;
    int lane = t & 63, w = t >> 6;
    int sv = v;
#pragma unroll
    for (int d = 1; d < 64; d <<= 1) {
        int u = __shfl_up(sv, d, 64);
        if (lane >= d) sv += u;
    }
    if (lane == 63) wsum[w] = sv;
    __syncthreads();
    int add = boff[b];
    for (int ww = 0; ww < w; ++ww) add += wsum[ww];
    if (i < N) off[i + 1] = add + sv;
    if (i == 0) off[0] = 0;
}

// ---------------- XCD-partitioned bucket fill ----------------
// Virtual block vb: group g = vb&7 owns dst range [g*6250, (g+1)*6250);
// chunk = vb>>3 selects 256 edges. With blockIdx%8 ~ XCD (heuristic), all
// csr/cnt2 stores for a dst range issue from one XCD -> lines stay L2-local.
// Correctness does not depend on the mapping.
__global__ __launch_bounds__(256)
void k_bucket(const int* __restrict__ srcv, const int* __restrict__ dstv,
              const int* __restrict__ off, int* cnt2, unsigned short* __restrict__ csr) {
    int vb = blockIdx.x;
    int g = vb & 7;
    int i = (vb >> 3) * 256 + threadIdx.x;   // < 800,000 exactly
    int d = dstv[i];
    if ((unsigned)(d - g * 6250) < 6250u) {
        int slot = off[d] + atomicAdd(&cnt2[d], 1);
        csr[slot] = (unsigned short)srcv[i];
    }
}

// ---------------- MFMA GEMM (layer 1): A[r][c] = fp16((X@W)[r][c] * dinv[r]) ----------------
template<int M>
__global__ __launch_bounds__(256)
void k_gemm_mfma(const unsigned short* __restrict__ Xh, const unsigned short* __restrict__ Xl,
                 const unsigned short* __restrict__ WTh, const unsigned short* __restrict__ WTl,
                 const float* __restrict__ dinv, f16* __restrict__ A, int N) {
    constexpr int NCB = M / 16;
    int wv = threadIdx.x >> 6, l = threadIdx.x & 63;
    int r0w = blockIdx.x * 64 + wv * 16;
    int arow = r0w + (l & 15);
    if (arow >= N) arow = N - 1;
    int kb = (l >> 4) * 8;

    bf16x8 ah[4], al[4];
#pragma unroll
    for (int ks = 0; ks < 4; ++ks) {
        ah[ks] = *(const bf16x8*)&Xh[(long)arow * 128 + ks * 32 + kb];
        al[ks] = *(const bf16x8*)&Xl[(long)arow * 128 + ks * 32 + kb];
    }
    f32x4 acc[NCB];
#pragma unroll
    for (int cb = 0; cb < NCB; ++cb) acc[cb] = f32x4{0.f, 0.f, 0.f, 0.f};
#pragma unroll
    for (int ks = 0; ks < 4; ++ks) {
#pragma unroll
        for (int cb = 0; cb < NCB; ++cb) {
            bf16x8 bh = *(const bf16x8*)&WTh[(long)(cb * 16 + (l & 15)) * 128 + ks * 32 + kb];
            bf16x8 bl = *(const bf16x8*)&WTl[(long)(cb * 16 + (l & 15)) * 128 + ks * 32 + kb];
            acc[cb] = __builtin_amdgcn_mfma_f32_16x16x32_bf16(ah[ks], bh, acc[cb], 0, 0, 0);
            acc[cb] = __builtin_amdgcn_mfma_f32_16x16x32_bf16(ah[ks], bl, acc[cb], 0, 0, 0);
            acc[cb] = __builtin_amdgcn_mfma_f32_16x16x32_bf16(al[ks], bh, acc[cb], 0, 0, 0);
        }
    }
    int rbase = r0w + (l >> 4) * 4;
    float dv[4];
#pragma unroll
    for (int i = 0; i < 4; ++i) dv[i] = (rbase + i < N) ? dinv[rbase + i] : 0.f;
#pragma unroll
    for (int cb = 0; cb < NCB; ++cb) {
#pragma unroll
        for (int i = 0; i < 4; ++i) {
            int r = rbase + i;
            if (r < N) A[(long)r * M + cb * 16 + (l & 15)] = (f16)(acc[cb][i] * dv[i]);
        }
    }
}

// ---------------- fused gather_i + GEMM_{i+1} ----------------
template<int MOUT>
__global__ __launch_bounds__(256)
void k_fused(const f16* __restrict__ Ain, const int* __restrict__ off,
             const unsigned short* __restrict__ csr, const float* __restrict__ dinv,
             const float* __restrict__ bias,
             const unsigned short* __restrict__ WTh, const unsigned short* __restrict__ WTl,
             f16* __restrict__ Aout, int N) {
    __shared__ unsigned short Hs[64 * 136];
    __shared__ unsigned short Ls[64 * 136];
    int r0 = blockIdx.x * 64;
    int t = threadIdx.x;
    int q = (t & 15) << 3;              // 8 channels / thread
    const f16* Aq = Ain + q;

    float4 bb0 = *(const float4*)&bias[q];
    float4 bb1 = *(const float4*)&bias[q + 4];
    float bv[8] = {bb0.x, bb0.y, bb0.z, bb0.w, bb1.x, bb1.y, bb1.z, bb1.w};

#pragma unroll
    for (int it = 0; it < 4; ++it) {
        int ln = it * 16 + (t >> 4);    // local node 0..63
        int node = r0 + ln;
        float acc[8] = {0.f, 0.f, 0.f, 0.f, 0.f, 0.f, 0.f, 0.f};
        if (node < N) {
            f16x8 v = *(const f16x8*)&Aq[(long)node * 128];   // self-loop
#pragma unroll
            for (int c = 0; c < 8; ++c) acc[c] = (float)v[c];
            int j = off[node], j1 = off[node + 1];
            for (; j + 8 <= j1; j += 8) {
                int s0 = csr[j + 0], s1 = csr[j + 1], s2 = csr[j + 2], s3 = csr[j + 3];
                int s4 = csr[j + 4], s5 = csr[j + 5], s6 = csr[j + 6], s7 = csr[j + 7];
                f16x8 v0 = *(const f16x8*)&Aq[(long)s0 * 128];
                f16x8 v1 = *(const f16x8*)&Aq[(long)s1 * 128];
                f16x8 v2 = *(const f16x8*)&Aq[(long)s2 * 128];
                f16x8 v3 = *(const f16x8*)&Aq[(long)s3 * 128];
                f16x8 v4 = *(const f16x8*)&Aq[(long)s4 * 128];
                f16x8 v5 = *(const f16x8*)&Aq[(long)s5 * 128];
                f16x8 v6 = *(const f16x8*)&Aq[(long)s6 * 128];
                f16x8 v7 = *(const f16x8*)&Aq[(long)s7 * 128];
#pragma unroll
                for (int c = 0; c < 8; ++c)
                    acc[c] += ((float)v0[c] + (float)v1[c] + (float)v2[c] + (float)v3[c])
                            + ((float)v4[c] + (float)v5[c] + (float)v6[c] + (float)v7[c]);
            }
            for (; j + 2 <= j1; j += 2) {
                int s0 = csr[j + 0], s1 = csr[j + 1];
                f16x8 v0 = *(const f16x8*)&Aq[(long)s0 * 128];
                f16x8 v1 = *(const f16x8*)&Aq[(long)s1 * 128];
#pragma unroll
                for (int c = 0; c < 8; ++c) acc[c] += (float)v0[c] + (float)v1[c];
            }
            if (j < j1) {
                int s = csr[j];
                f16x8 vv = *(const f16x8*)&Aq[(long)s * 128];
#pragma unroll
                for (int c = 0; c < 8; ++c) acc[c] += (float)vv[c];
            }
            float sc = dinv[node];
#pragma unroll
            for (int c = 0; c < 8; ++c) acc[c] = fmaxf(acc[c] * sc + bv[c], 0.f);
        }
        u16x8 h, lo;
#pragma unroll
        for (int c = 0; c < 8; ++c) {
            unsigned short hh = f2bf_rne(acc[c]);
            h[c] = hh;
            lo[c] = f2bf_rne(acc[c] - bf2f(hh));
        }
        *(u16x8*)&Hs[ln * 136 + q] = h;
        *(u16x8*)&Ls[ln * 136 + q] = lo;
    }
    __syncthreads();

    // phase 2: GEMM from LDS
    constexpr int NCB = MOUT / 16;
    int wv = t >> 6, l = t & 63;
    int lrow = wv * 16 + (l & 15);
    int kb = (l >> 4) * 8;
    bf16x8 ah[4], al[4];
#pragma unroll
    for (int ks = 0; ks < 4; ++ks) {
        ah[ks] = *(const bf16x8*)&Hs[lrow * 136 + ks * 32 + kb];
        al[ks] = *(const bf16x8*)&Ls[lrow * 136 + ks * 32 + kb];
    }
    f32x4 acc2[NCB];
#pragma unroll
    for (int cb = 0; cb < NCB; ++cb) acc2[cb] = f32x4{0.f, 0.f, 0.f, 0.f};
#pragma unroll
    for (int ks = 0; ks < 4; ++ks) {
#pragma unroll
        for (int cb = 0; cb < NCB; ++cb) {
            bf16x8 bh = *(const bf16x8*)&WTh[(long)(cb * 16 + (l & 15)) * 128 + ks * 32 + kb];
            bf16x8 bl = *(const bf16x8*)&WTl[(long)(cb * 16 + (l & 15)) * 128 + ks * 32 + kb];
            acc2[cb] = __builtin_amdgcn_mfma_f32_16x16x32_bf16(ah[ks], bh, acc2[cb], 0, 0, 0);
            acc2[cb] = __builtin_amdgcn_mfma_f32_16x16x32_bf16(ah[ks], bl, acc2[cb], 0, 0, 0);
            acc2[cb] = __builtin_amdgcn_mfma_f32_16x16x32_bf16(al[ks], bh, acc2[cb], 0, 0, 0);
        }
    }
    int rbase = r0 + wv * 16 + (l >> 4) * 4;
    float dv[4];
#pragma unroll
    for (int i = 0; i < 4; ++i) dv[i] = (rbase + i < N) ? dinv[rbase + i] : 0.f;
#pragma unroll
    for (int cb = 0; cb < NCB; ++cb) {
#pragma unroll
        for (int i = 0; i < 4; ++i) {
            int r = rbase + i;
            if (r < N) Aout[(long)r * MOUT + cb * 16 + (l & 15)] = (f16)(acc2[cb][i] * dv[i]);
        }
    }
}

// ---------------- final gather (layer 3): A3 fp16 64ch -> z fp32, no relu ----------------
__global__ __launch_bounds__(256)
void k_gather3(const f16* __restrict__ A, const int* __restrict__ off,
               const unsigned short* __restrict__ csr, const float* __restrict__ dinv,
               const float* __restrict__ bias, float* __restrict__ z, int N) {
    int t = blockIdx.x * blockDim.x + threadIdx.x;
    int node = t >> 3;
    if (node >= N) return;
    int q = (t & 7) << 3;
    const f16* Aq = A + q;

    float acc[8];
    {
        f16x8 v = *(const f16x8*)&Aq[(long)node * 64];
#pragma unroll
        for (int c = 0; c < 8; ++c) acc[c] = (float)v[c];
    }
    int j = off[node], j1 = off[node + 1];
    for (; j + 8 <= j1; j += 8) {
        int s0 = csr[j + 0], s1 = csr[j + 1], s2 = csr[j + 2], s3 = csr[j + 3];
        int s4 = csr[j + 4], s5 = csr[j + 5], s6 = csr[j + 6], s7 = csr[j + 7];
        f16x8 v0 = *(const f16x8*)&Aq[(long)s0 * 64];
        f16x8 v1 = *(const f16x8*)&Aq[(long)s1 * 64];
        f16x8 v2 = *(const f16x8*)&Aq[(long)s2 * 64];
        f16x8 v3 = *(const f16x8*)&Aq[(long)s3 * 64];
        f16x8 v4 = *(const f16x8*)&Aq[(long)s4 * 64];
        f16x8 v5 = *(const f16x8*)&Aq[(long)s5 * 64];
        f16x8 v6 = *(const f16x8*)&Aq[(long)s6 * 64];
        f16x8 v7 = *(const f16x8*)&Aq[(long)s7 * 64];
#pragma unroll
        for (int c = 0; c < 8; ++c)
            acc[c] += ((float)v0[c] + (float)v1[c] + (float)v2[c] + (float)v3[c])
                    + ((float)v4[c] + (float)v5[c] + (float)v6[c] + (float)v7[c]);
    }
    for (; j + 2 <= j1; j += 2) {
        int s0 = csr[j + 0], s1 = csr[j + 1];
        f16x8 v0 = *(const f16x8*)&Aq[(long)s0 * 64];
        f16x8 v1 = *(const f16x8*)&Aq[(long)s1 * 64];
#pragma unroll
        for (int c = 0; c < 8; ++c) acc[c] += (float)v0[c] + (float)v1[c];
    }
    if (j < j1) {
        int s = csr[j];
        f16x8 v = *(const f16x8*)&Aq[(long)s * 64];
#pragma unroll
        for (int c = 0; c < 8; ++c) acc[c] += (float)v[c];
    }

    float sc = dinv[node];
    float4 bb0 = *(const float4*)&bias[q];
    float4 bb1 = *(const float4*)&bias[q + 4];
    float bv[8] = {bb0.x, bb0.y, bb0.z, bb0.w, bb1.x, bb1.y, bb1.z, bb1.w};
    float4 o0, o1;
    o0.x = acc[0] * sc + bv[0]; o0.y = acc[1] * sc + bv[1];
    o0.z = acc[2] * sc + bv[2]; o0.w = acc[3] * sc + bv[3];
    o1.x = acc[4] * sc + bv[4]; o1.y = acc[5] * sc + bv[5];
    o1.z = acc[6] * sc + bv[6]; o1.w = acc[7] * sc + bv[7];
    *(float4*)&z[(long)node * 64 + q] = o0;
    *(float4*)&z[(long)node * 64 + q + 4] = o1;
}

// ---------------- decode: out[i] = dot64(z[a], z[b]) ----------------
__global__ void k_decode(const float* __restrict__ z, const int* __restrict__ eli,
                         float* __restrict__ out, int L) {
    int t = blockIdx.x * blockDim.x + threadIdx.x;
    int e = t >> 4;
    int lane = t & 15;
    if (e >= L) return;
    int a = eli[e], b = eli[L + e];
    float4 va = *(const float4*)&z[(long)a * 64 + lane * 4];
    float4 vb = *(const float4*)&z[(long)b * 64 + lane * 4];
    float s = va.x * vb.x + va.y * vb.y + va.z * vb.z + va.w * vb.w;
    s += __shfl_xor(s, 1, 16);
    s += __shfl_xor(s, 2, 16);
    s += __shfl_xor(s, 4, 16);
    s += __shfl_xor(s, 8, 16);
    if (lane == 0) out[e] = s;
}

extern "C" void kernel_launch(void* const* d_in, const int* in_sizes, int n_in,
                              void* d_out, int out_size, void* d_ws, size_t ws_size,
                              hipStream_t stream) {
    const float* x   = (const float*)d_in[0];
    const float* W1  = (const float*)d_in[1];
    const float* b1  = (const float*)d_in[2];
    const float* W2  = (const float*)d_in[3];
    const float* b2  = (const float*)d_in[4];
    const float* W3  = (const float*)d_in[5];
    const float* b3  = (const float*)d_in[6];
    const int*   ei  = (const int*)d_in[7];
    const int*   eli = (const int*)d_in[8];
    float* out = (float*)d_out;

    char* ws = (char*)d_ws;
    float* dinv = (float*)ws;                  ws += 50048 * 4;
    f16*   A1   = (f16*)ws;                    ws += (long)N_NODES * 128 * 2;
    f16*   A2   = (f16*)ws;                    ws += (long)N_NODES * 128 * 2;
    float* z    = (float*)ws;                  ws += (long)N_NODES * 64 * 4;
    unsigned short* inh = (unsigned short*)ws; ws += (long)N_NODES * 128 * 2;
    unsigned short* inl = (unsigned short*)ws; ws += (long)N_NODES * 128 * 2;
    int*   cnt  = (int*)ws;                    ws += 50048 * 4;
    int*   cnt2 = (int*)ws;                    ws += 50048 * 4;   // contiguous with cnt
    int*   off  = (int*)ws;                    ws += 50048 * 4;
    unsigned short* csr = (unsigned short*)ws; ws += (long)N_EDGES * 2;
    int*   bsum = (int*)ws;                    ws += 256 * 4;
    int*   boff = (int*)ws;                    ws += 256 * 4;
    unsigned short* WT1h = (unsigned short*)ws; ws += 16384 * 2;
    unsigned short* WT1l = (unsigned short*)ws; ws += 16384 * 2;
    unsigned short* WT2h = (unsigned short*)ws; ws += 16384 * 2;
    unsigned short* WT2l = (unsigned short*)ws; ws += 16384 * 2;
    unsigned short* WT3h = (unsigned short*)ws; ws += 8192 * 2;
    unsigned short* WT3l = (unsigned short*)ws; ws += 8192 * 2;

    const int* esrc = ei;
    const int* edst = ei + N_EDGES;

    const int NB = (N_NODES + 255) / 256;  // 196

    // zero cnt+cnt2 (contiguous), then fused prep (xprep + wprep + deg_count)
    hipMemsetAsync(cnt, 0, 2 * 50048 * sizeof(int), stream);
    k_prep     <<<9439, 256, 0, stream>>>(x, inh, inl, W1, W2, W3,
                                          WT1h, WT1l, WT2h, WT2l, WT3h, WT3l, edst, cnt);
    k_partial  <<<NB, 256, 0, stream>>>(cnt, dinv, bsum, N_NODES);
    k_scan_bsum<<<1, 256, 0, stream>>>(bsum, boff, NB);
    k_offsets  <<<NB, 256, 0, stream>>>(cnt, boff, off, N_NODES);

    // XCD-partitioned bucket fill (8 dst-range groups x 3125 chunks)
    k_bucket<<<25000, 256, 0, stream>>>(esrc, edst, off, cnt2, csr);

    // GEMM1: X@W1 -> A1
    k_gemm_mfma<128><<<GEMM_BLOCKS, 256, 0, stream>>>(inh, inl, WT1h, WT1l, dinv, A1, N_NODES);

    // fused gather1+GEMM2 and gather2+GEMM3
    k_fused<128><<<GEMM_BLOCKS, 256, 0, stream>>>(A1, off, csr, dinv, b1, WT2h, WT2l, A2, N_NODES);
    k_fused<64> <<<GEMM_BLOCKS, 256, 0, stream>>>(A2, off, csr, dinv, b2, WT3h, WT3l, A1, N_NODES);

    // final gather (layer 3) -> z, then decode
    k_gather3<<<(N_NODES * 8 + 255) / 256, 256, 0, stream>>>(A1, off, csr, dinv, b3, z, N_NODES);
    k_decode <<<(N_LABEL * 16 + 255) / 256, 256, 0, stream>>>(z, eli, out, N_LABEL);
}

// Round 8
// 291.317 us; speedup vs baseline: 1.2413x; 1.0005x over previous
//
#include <hip/hip_runtime.h>

#define N_NODES 50000
#define N_EDGES 800000
#define N_LABEL 200000
#define GEMM_BLOCKS 782   // ceil(50000/64)

typedef __attribute__((ext_vector_type(8))) short bf16x8;
typedef __attribute__((ext_vector_type(4))) float f32x4;
typedef _Float16 f16;
typedef __attribute__((ext_vector_type(8))) _Float16 f16x8;
typedef __attribute__((ext_vector_type(8))) unsigned short u16x8;

__device__ inline unsigned short f2bf_rne(float f) {
    union { float f; unsigned u; } v; v.f = f;
    unsigned r = v.u + 0x7fffu + ((v.u >> 16) & 1u);
    return (unsigned short)(r >> 16);
}
__device__ inline float bf2f(unsigned short h) {
    union { unsigned u; float f; } v; v.u = ((unsigned)h) << 16;
    return v.f;
}

// ---------------- degree count (cnt pre-zeroed by memset) ----------------
__global__ __launch_bounds__(256)
void k_deg(const int* __restrict__ dst, int* cnt) {
    int i = blockIdx.x * 256 + threadIdx.x;   // < 800,000 exactly
    atomicAdd(&cnt[dst[i]], 1);
}

// ---------------- scan chain ----------------
__global__ __launch_bounds__(256)
void k_partial(const int* __restrict__ cnt, float* __restrict__ dinv,
               int* __restrict__ bsum, int N) {
    __shared__ int wsum[4];
    int b = blockIdx.x, t = threadIdx.x;
    int i = b * 256 + t;
    int v = (i < N) ? cnt[i] : 0;
    if (i < N) dinv[i] = rsqrtf((float)v + 1.0f);
    int s = v;
#pragma unroll
    for (int d = 1; d < 64; d <<= 1) s += __shfl_xor(s, d, 64);
    if ((t & 63) == 0) wsum[t >> 6] = s;
    __syncthreads();
    if (t == 0) bsum[b] = wsum[0] + wsum[1] + wsum[2] + wsum[3];
}

__global__ __launch_bounds__(256)
void k_scan_bsum(const int* __restrict__ bsum, int* __restrict__ boff, int NB) {
    __shared__ int wsum[4];
    int t = threadIdx.x;
    int v = (t < NB) ? bsum[t] : 0;
    int lane = t & 63, w = t >> 6;
    int sv = v;
#pragma unroll
    for (int d = 1; d < 64; d <<= 1) {
        int u = __shfl_up(sv, d, 64);
        if (lane >= d) sv += u;
    }
    if (lane == 63) wsum[w] = sv;
    __syncthreads();
    int add = 0;
    for (int ww = 0; ww < w; ++ww) add += wsum[ww];
    if (t < NB) boff[t] = sv + add - v;
}

__global__ __launch_bounds__(256)
void k_offsets(const int* __restrict__ cnt, const int* __restrict__ boff,
               int* __restrict__ off, int N) {
    __shared__ int wsum[4];
    int b = blockIdx.x, t = threadIdx.x;
    int i = b * 256 + t;
    int v = (i < N) ? cnt[i] : 0;
    int lane = t & 63, w = t >> 6;
    int sv = v;
#pragma unroll
    for (int d = 1; d < 64; d <<= 1) {
        int u = __shfl_up(sv, d, 64);
        if (lane >= d) sv += u;
    }
    if (lane == 63) wsum[w] = sv;
    __syncthreads();
    int add = boff[b];
    for (int ww = 0; ww < w; ++ww) add += wsum[ww];
    if (i < N) off[i + 1] = add + sv;
    if (i == 0) off[0] = 0;
}

// ---------------- mix: xprep | wprep | XCD-partitioned bucket fill ----------------
// All three are low-VGPR, zero-LDS, memory-bound -> co-residency is safe (R7 lesson:
// never pair a latency-bound scatter with a VGPR/LDS-heavy phase).
// blocks [0,6250): xprep; [6250,6314): wprep; [6314,31314): bucket.
// Bucket: virtual block vb, group g=vb&7 owns dst range [g*6250,(g+1)*6250);
// blockIdx%8 ~ XCD (heuristic) keeps csr/cnt2 store lines XCD-local.
__global__ __launch_bounds__(256)
void k_mix(const float* __restrict__ x, unsigned short* __restrict__ Xh,
           unsigned short* __restrict__ Xl,
           const float* __restrict__ W1, const float* __restrict__ W2,
           const float* __restrict__ W3,
           unsigned short* WT1h, unsigned short* WT1l,
           unsigned short* WT2h, unsigned short* WT2l,
           unsigned short* WT3h, unsigned short* WT3l,
           const int* __restrict__ srcv, const int* __restrict__ dstv,
           const int* __restrict__ off, int* cnt2, unsigned short* __restrict__ csr) {
    int b = blockIdx.x, tid = threadIdx.x;
    if (b < 6250) {
        long t = (long)b * 256 + tid;          // < 1,600,000 exactly
        float4 v = *(const float4*)&x[t * 4];
        ushort4 h, lo;
        h.x = f2bf_rne(v.x); lo.x = f2bf_rne(v.x - bf2f(h.x));
        h.y = f2bf_rne(v.y); lo.y = f2bf_rne(v.y - bf2f(h.y));
        h.z = f2bf_rne(v.z); lo.z = f2bf_rne(v.z - bf2f(h.z));
        h.w = f2bf_rne(v.w); lo.w = f2bf_rne(v.w - bf2f(h.w));
        *(ushort4*)&Xh[t * 4] = h;
        *(ushort4*)&Xl[t * 4] = lo;
    } else if (b < 6314) {
        int t = (b - 6250) * 256 + tid;        // < 16384
        int c = t >> 7, k = t & 127;
        float w = W1[k * 128 + c];
        unsigned short h = f2bf_rne(w);
        WT1h[c * 128 + k] = h; WT1l[c * 128 + k] = f2bf_rne(w - bf2f(h));
        w = W2[k * 128 + c];
        h = f2bf_rne(w);
        WT2h[c * 128 + k] = h; WT2l[c * 128 + k] = f2bf_rne(w - bf2f(h));
        if (c < 64) {
            w = W3[k * 64 + c];
            h = f2bf_rne(w);
            WT3h[c * 128 + k] = h; WT3l[c * 128 + k] = f2bf_rne(w - bf2f(h));
        }
    } else {
        int vb = b - 6314;                     // [0, 25000)
        int g = vb & 7;
        int i = (vb >> 3) * 256 + tid;         // < 800,000 exactly
        int d = dstv[i];
        if ((unsigned)(d - g * 6250) < 6250u) {
            int slot = off[d] + atomicAdd(&cnt2[d], 1);
            csr[slot] = (unsigned short)srcv[i];
        }
    }
}

// ---------------- MFMA GEMM: A[r][c] = fp16((X@W)[r][c] * dinv[r]) ----------------
// X as hi/lo bf16 [N][128]; W as WT[col][128] hi/lo bf16. 4 waves, 16 rows/wave.
template<int M>
__global__ __launch_bounds__(256)
void k_gemm_mfma(const unsigned short* __restrict__ Xh, const unsigned short* __restrict__ Xl,
                 const unsigned short* __restrict__ WTh, const unsigned short* __restrict__ WTl,
                 const float* __restrict__ dinv, f16* __restrict__ A, int N) {
    constexpr int NCB = M / 16;
    int wv = threadIdx.x >> 6, l = threadIdx.x & 63;
    int r0w = blockIdx.x * 64 + wv * 16;
    int arow = r0w + (l & 15);
    if (arow >= N) arow = N - 1;
    int kb = (l >> 4) * 8;

    bf16x8 ah[4], al[4];
#pragma unroll
    for (int ks = 0; ks < 4; ++ks) {
        ah[ks] = *(const bf16x8*)&Xh[(long)arow * 128 + ks * 32 + kb];
        al[ks] = *(const bf16x8*)&Xl[(long)arow * 128 + ks * 32 + kb];
    }
    f32x4 acc[NCB];
#pragma unroll
    for (int cb = 0; cb < NCB; ++cb) acc[cb] = f32x4{0.f, 0.f, 0.f, 0.f};
#pragma unroll
    for (int ks = 0; ks < 4; ++ks) {
#pragma unroll
        for (int cb = 0; cb < NCB; ++cb) {
            bf16x8 bh = *(const bf16x8*)&WTh[(long)(cb * 16 + (l & 15)) * 128 + ks * 32 + kb];
            bf16x8 bl = *(const bf16x8*)&WTl[(long)(cb * 16 + (l & 15)) * 128 + ks * 32 + kb];
            acc[cb] = __builtin_amdgcn_mfma_f32_16x16x32_bf16(ah[ks], bh, acc[cb], 0, 0, 0);
            acc[cb] = __builtin_amdgcn_mfma_f32_16x16x32_bf16(ah[ks], bl, acc[cb], 0, 0, 0);
            acc[cb] = __builtin_amdgcn_mfma_f32_16x16x32_bf16(al[ks], bh, acc[cb], 0, 0, 0);
        }
    }
    // C/D layout: col = l&15, row = (l>>4)*4 + i   [verified m89]
    int rbase = r0w + (l >> 4) * 4;
    float dv[4];
#pragma unroll
    for (int i = 0; i < 4; ++i) dv[i] = (rbase + i < N) ? dinv[rbase + i] : 0.f;
#pragma unroll
    for (int cb = 0; cb < NCB; ++cb) {
#pragma unroll
        for (int i = 0; i < 4; ++i) {
            int r = rbase + i;
            if (r < N) A[(long)r * M + cb * 16 + (l & 15)] = (f16)(acc[cb][i] * dv[i]);
        }
    }
}

// ---------------- gather + finish (A fp16, 8 ch/thread, high occupancy) ----------------
// mode 0: write fp32 Bf;  mode 1: write hi/lo bf16 (Bh, Bl) for next GEMM
__global__ __launch_bounds__(256)
void k_gather(const f16* __restrict__ A, const int* __restrict__ off,
              const unsigned short* __restrict__ csr, const float* __restrict__ dinv,
              const float* __restrict__ bias, float* __restrict__ Bf,
              unsigned short* __restrict__ Bh, unsigned short* __restrict__ Bl,
              int N, int M, int lg, int relu, int mode) {
    int t = blockIdx.x * blockDim.x + threadIdx.x;
    int node = t >> lg;
    if (node >= N) return;
    int q = (t & ((1 << lg) - 1)) << 3;   // 8 channels per thread
    const f16* Aq = A + q;

    float acc[8];
    {
        f16x8 v = *(const f16x8*)&Aq[(long)node * M];  // self-loop
#pragma unroll
        for (int c = 0; c < 8; ++c) acc[c] = (float)v[c];
    }
    int j = off[node], j1 = off[node + 1];
    for (; j + 8 <= j1; j += 8) {
        int s0 = csr[j + 0], s1 = csr[j + 1], s2 = csr[j + 2], s3 = csr[j + 3];
        int s4 = csr[j + 4], s5 = csr[j + 5], s6 = csr[j + 6], s7 = csr[j + 7];
        f16x8 v0 = *(const f16x8*)&Aq[(long)s0 * M];
        f16x8 v1 = *(const f16x8*)&Aq[(long)s1 * M];
        f16x8 v2 = *(const f16x8*)&Aq[(long)s2 * M];
        f16x8 v3 = *(const f16x8*)&Aq[(long)s3 * M];
        f16x8 v4 = *(const f16x8*)&Aq[(long)s4 * M];
        f16x8 v5 = *(const f16x8*)&Aq[(long)s5 * M];
        f16x8 v6 = *(const f16x8*)&Aq[(long)s6 * M];
        f16x8 v7 = *(const f16x8*)&Aq[(long)s7 * M];
#pragma unroll
        for (int c = 0; c < 8; ++c)
            acc[c] += ((float)v0[c] + (float)v1[c] + (float)v2[c] + (float)v3[c])
                    + ((float)v4[c] + (float)v5[c] + (float)v6[c] + (float)v7[c]);
    }
    for (; j + 2 <= j1; j += 2) {
        int s0 = csr[j + 0], s1 = csr[j + 1];
        f16x8 v0 = *(const f16x8*)&Aq[(long)s0 * M];
        f16x8 v1 = *(const f16x8*)&Aq[(long)s1 * M];
#pragma unroll
        for (int c = 0; c < 8; ++c) acc[c] += (float)v0[c] + (float)v1[c];
    }
    if (j < j1) {
        int s = csr[j];
        f16x8 v = *(const f16x8*)&Aq[(long)s * M];
#pragma unroll
        for (int c = 0; c < 8; ++c) acc[c] += (float)v[c];
    }

    float sc = dinv[node];
    float4 bb0 = *(const float4*)&bias[q];
    float4 bb1 = *(const float4*)&bias[q + 4];
    float bv[8] = {bb0.x, bb0.y, bb0.z, bb0.w, bb1.x, bb1.y, bb1.z, bb1.w};
#pragma unroll
    for (int c = 0; c < 8; ++c) {
        acc[c] = acc[c] * sc + bv[c];
        if (relu) acc[c] = fmaxf(acc[c], 0.f);
    }
    if (mode == 0) {
        float4 o0 = make_float4(acc[0], acc[1], acc[2], acc[3]);
        float4 o1 = make_float4(acc[4], acc[5], acc[6], acc[7]);
        *(float4*)&Bf[(long)node * M + q] = o0;
        *(float4*)&Bf[(long)node * M + q + 4] = o1;
    } else {
        u16x8 h, lo;
#pragma unroll
        for (int c = 0; c < 8; ++c) {
            unsigned short hh = f2bf_rne(acc[c]);
            h[c] = hh;
            lo[c] = f2bf_rne(acc[c] - bf2f(hh));
        }
        *(u16x8*)&Bh[(long)node * M + q] = h;
        *(u16x8*)&Bl[(long)node * M + q] = lo;
    }
}

// ---------------- decode: out[i] = dot64(z[a], z[b]) ----------------
__global__ void k_decode(const float* __restrict__ z, const int* __restrict__ eli,
                         float* __restrict__ out, int L) {
    int t = blockIdx.x * blockDim.x + threadIdx.x;
    int e = t >> 4;
    int lane = t & 15;
    if (e >= L) return;
    int a = eli[e], b = eli[L + e];
    float4 va = *(const float4*)&z[(long)a * 64 + lane * 4];
    float4 vb = *(const float4*)&z[(long)b * 64 + lane * 4];
    float s = va.x * vb.x + va.y * vb.y + va.z * vb.z + va.w * vb.w;
    s += __shfl_xor(s, 1, 16);
    s += __shfl_xor(s, 2, 16);
    s += __shfl_xor(s, 4, 16);
    s += __shfl_xor(s, 8, 16);
    if (lane == 0) out[e] = s;
}

extern "C" void kernel_launch(void* const* d_in, const int* in_sizes, int n_in,
                              void* d_out, int out_size, void* d_ws, size_t ws_size,
                              hipStream_t stream) {
    const float* x   = (const float*)d_in[0];
    const float* W1  = (const float*)d_in[1];
    const float* b1  = (const float*)d_in[2];
    const float* W2  = (const float*)d_in[3];
    const float* b2  = (const float*)d_in[4];
    const float* W3  = (const float*)d_in[5];
    const float* b3  = (const float*)d_in[6];
    const int*   ei  = (const int*)d_in[7];
    const int*   eli = (const int*)d_in[8];
    float* out = (float*)d_out;

    char* ws = (char*)d_ws;
    float* dinv = (float*)ws;                  ws += 50048 * 4;
    f16*   A    = (f16*)ws;                    ws += (long)N_NODES * 128 * 2;
    float* z    = (float*)ws;                  ws += (long)N_NODES * 64 * 4;
    unsigned short* inh = (unsigned short*)ws; ws += (long)N_NODES * 128 * 2;
    unsigned short* inl = (unsigned short*)ws; ws += (long)N_NODES * 128 * 2;
    int*   cnt  = (int*)ws;                    ws += 50048 * 4;
    int*   cnt2 = (int*)ws;                    ws += 50048 * 4;   // contiguous with cnt
    int*   off  = (int*)ws;                    ws += 50048 * 4;
    unsigned short* csr = (unsigned short*)ws; ws += (long)N_EDGES * 2;
    int*   bsum = (int*)ws;                    ws += 256 * 4;
    int*   boff = (int*)ws;                    ws += 256 * 4;
    unsigned short* WT1h = (unsigned short*)ws; ws += 16384 * 2;
    unsigned short* WT1l = (unsigned short*)ws; ws += 16384 * 2;
    unsigned short* WT2h = (unsigned short*)ws; ws += 16384 * 2;
    unsigned short* WT2l = (unsigned short*)ws; ws += 16384 * 2;
    unsigned short* WT3h = (unsigned short*)ws; ws += 8192 * 2;
    unsigned short* WT3l = (unsigned short*)ws; ws += 8192 * 2;

    const int* esrc = ei;
    const int* edst = ei + N_EDGES;

    const int NB = (N_NODES + 255) / 256;  // 196

    // degree -> scan -> offsets
    hipMemsetAsync(cnt, 0, 2 * 50048 * sizeof(int), stream);
    k_deg      <<<3125, 256, 0, stream>>>(edst, cnt);
    k_partial  <<<NB, 256, 0, stream>>>(cnt, dinv, bsum, N_NODES);
    k_scan_bsum<<<1, 256, 0, stream>>>(bsum, boff, NB);
    k_offsets  <<<NB, 256, 0, stream>>>(cnt, boff, off, N_NODES);

    // xprep | wprep | bucket (all low-VGPR memory-bound; co-resident)
    k_mix<<<31314, 256, 0, stream>>>(x, inh, inl, W1, W2, W3,
                                     WT1h, WT1l, WT2h, WT2l, WT3h, WT3l,
                                     esrc, edst, off, cnt2, csr);

    const int ga128 = (N_NODES * 16 + 255) / 256;   // 16 thr/node
    const int ga64  = (N_NODES * 8 + 255) / 256;    // 8 thr/node

    // layer 1
    k_gemm_mfma<128><<<GEMM_BLOCKS, 256, 0, stream>>>(inh, inl, WT1h, WT1l, dinv, A, N_NODES);
    k_gather<<<ga128, 256, 0, stream>>>(A, off, csr, dinv, b1, nullptr, inh, inl,
                                        N_NODES, 128, 4, 1, 1);
    // layer 2
    k_gemm_mfma<128><<<GEMM_BLOCKS, 256, 0, stream>>>(inh, inl, WT2h, WT2l, dinv, A, N_NODES);
    k_gather<<<ga128, 256, 0, stream>>>(A, off, csr, dinv, b2, nullptr, inh, inl,
                                        N_NODES, 128, 4, 1, 1);
    // layer 3 (M=64, no relu, fp32 out)
    k_gemm_mfma<64><<<GEMM_BLOCKS, 256, 0, stream>>>(inh, inl, WT3h, WT3l, dinv, A, N_NODES);
    k_gather<<<ga64, 256, 0, stream>>>(A, off, csr, dinv, b3, z, nullptr, nullptr,
                                       N_NODES, 64, 3, 0, 0);

    // decode
    k_decode<<<(N_LABEL * 16 + 255) / 256, 256, 0, stream>>>(z, eli, out, N_LABEL);
}

// Round 9
// 290.888 us; speedup vs baseline: 1.2432x; 1.0015x over previous
//
#include <hip/hip_runtime.h>

#define N_NODES 50000
#define N_EDGES 800000
#define N_LABEL 200000
#define GEMM_BLOCKS 782   // ceil(50000/64)

typedef __attribute__((ext_vector_type(8))) short bf16x8;
typedef __attribute__((ext_vector_type(4))) float f32x4;
typedef _Float16 f16;
typedef __attribute__((ext_vector_type(8))) _Float16 f16x8;
typedef __attribute__((ext_vector_type(8))) unsigned short u16x8;

__device__ inline unsigned short f2bf_rne(float f) {
    union { float f; unsigned u; } v; v.f = f;
    unsigned r = v.u + 0x7fffu + ((v.u >> 16) & 1u);
    return (unsigned short)(r >> 16);
}
__device__ inline float bf2f(unsigned short h) {
    union { unsigned u; float f; } v; v.u = ((unsigned)h) << 16;
    return v.f;
}

// ---------------- fused prep: x->hi/lo bf16 | W transpose/split | deg_count ----------------
// All streaming/atomic, low-VGPR, no LDS-resident state to thrash (R8 lesson: keep the
// L2-locality-dependent bucket OUT of this kernel).
// blocks [0,6250): xprep; [6250,6314): wprep; [6314,9439): deg_count (cnt pre-zeroed)
__global__ __launch_bounds__(256)
void k_prep(const float* __restrict__ x, unsigned short* __restrict__ Xh,
            unsigned short* __restrict__ Xl,
            const float* __restrict__ W1, const float* __restrict__ W2,
            const float* __restrict__ W3,
            unsigned short* WT1h, unsigned short* WT1l,
            unsigned short* WT2h, unsigned short* WT2l,
            unsigned short* WT3h, unsigned short* WT3l,
            const int* __restrict__ dst, int* cnt) {
    int b = blockIdx.x, tid = threadIdx.x;
    if (b < 6250) {
        long t = (long)b * 256 + tid;          // < 1,600,000 exactly
        float4 v = *(const float4*)&x[t * 4];
        ushort4 h, lo;
        h.x = f2bf_rne(v.x); lo.x = f2bf_rne(v.x - bf2f(h.x));
        h.y = f2bf_rne(v.y); lo.y = f2bf_rne(v.y - bf2f(h.y));
        h.z = f2bf_rne(v.z); lo.z = f2bf_rne(v.z - bf2f(h.z));
        h.w = f2bf_rne(v.w); lo.w = f2bf_rne(v.w - bf2f(h.w));
        *(ushort4*)&Xh[t * 4] = h;
        *(ushort4*)&Xl[t * 4] = lo;
    } else if (b < 6314) {
        int t = (b - 6250) * 256 + tid;        // < 16384
        int c = t >> 7, k = t & 127;
        float w = W1[k * 128 + c];
        unsigned short h = f2bf_rne(w);
        WT1h[c * 128 + k] = h; WT1l[c * 128 + k] = f2bf_rne(w - bf2f(h));
        w = W2[k * 128 + c];
        h = f2bf_rne(w);
        WT2h[c * 128 + k] = h; WT2l[c * 128 + k] = f2bf_rne(w - bf2f(h));
        if (c < 64) {
            w = W3[k * 64 + c];
            h = f2bf_rne(w);
            WT3h[c * 128 + k] = h; WT3l[c * 128 + k] = f2bf_rne(w - bf2f(h));
        }
    } else {
        int i = (b - 6314) * 256 + tid;        // < 800,000 exactly
        atomicAdd(&cnt[dst[i]], 1);
    }
}

// ---------------- scan chain (2 kernels) ----------------
__global__ __launch_bounds__(256)
void k_partial(const int* __restrict__ cnt, float* __restrict__ dinv,
               int* __restrict__ bsum, int N) {
    __shared__ int wsum[4];
    int b = blockIdx.x, t = threadIdx.x;
    int i = b * 256 + t;
    int v = (i < N) ? cnt[i] : 0;
    if (i < N) dinv[i] = rsqrtf((float)v + 1.0f);
    int s = v;
#pragma unroll
    for (int d = 1; d < 64; d <<= 1) s += __shfl_xor(s, d, 64);
    if ((t & 63) == 0) wsum[t >> 6] = s;
    __syncthreads();
    if (t == 0) bsum[b] = wsum[0] + wsum[1] + wsum[2] + wsum[3];
}

// merged: block b computes add0 = sum(bsum[0..b)) by block-reduce, then local scan
__global__ __launch_bounds__(256)
void k_offsets(const int* __restrict__ cnt, const int* __restrict__ bsum,
               int* __restrict__ off, int N, int NB) {
    __shared__ int wsum[4];
    __shared__ int add0_s;
    int b = blockIdx.x, t = threadIdx.x;
    // phase A: exclusive prefix of block sums
    int v0 = (t < b && t < NB) ? bsum[t] : 0;
    int s0 = v0;
#pragma unroll
    for (int d = 1; d < 64; d <<= 1) s0 += __shfl_xor(s0, d, 64);
    if ((t & 63) == 0) wsum[t >> 6] = s0;
    __syncthreads();
    if (t == 0) add0_s = wsum[0] + wsum[1] + wsum[2] + wsum[3];
    __syncthreads();
    int add = add0_s;
    __syncthreads();  // protect wsum reuse
    // phase B: local inclusive scan of cnt
    int i = b * 256 + t;
    int v = (i < N) ? cnt[i] : 0;
    int lane = t & 63, w = t >> 6;
    int sv = v;
#pragma unroll
    for (int d = 1; d < 64; d <<= 1) {
        int u = __shfl_up(sv, d, 64);
        if (lane >= d) sv += u;
    }
    if (lane == 63) wsum[w] = sv;
    __syncthreads();
    for (int ww = 0; ww < w; ++ww) add += wsum[ww];
    if (i < N) off[i + 1] = add + sv;
    if (i == 0) off[0] = 0;
}

// ---------------- XCD-partitioned bucket fill (STANDALONE — R8 lesson) ----------------
// Virtual block vb: group g = vb&7 owns dst range [g*6250,(g+1)*6250);
// blockIdx%8 ~ XCD keeps each group's csr/cnt2 slice (~200KB) L2-resident.
__global__ __launch_bounds__(256)
void k_bucket(const int* __restrict__ srcv, const int* __restrict__ dstv,
              const int* __restrict__ off, int* cnt2, unsigned short* __restrict__ csr) {
    int vb = blockIdx.x;
    int g = vb & 7;
    int i = (vb >> 3) * 256 + threadIdx.x;   // < 800,000 exactly
    int d = dstv[i];
    if ((unsigned)(d - g * 6250) < 6250u) {
        int slot = off[d] + atomicAdd(&cnt2[d], 1);
        csr[slot] = (unsigned short)srcv[i];
    }
}

// ---------------- MFMA GEMM: A[r][c] = fp16((X@W)[r][c] * dinv[r]) ----------------
template<int M>
__global__ __launch_bounds__(256)
void k_gemm_mfma(const unsigned short* __restrict__ Xh, const unsigned short* __restrict__ Xl,
                 const unsigned short* __restrict__ WTh, const unsigned short* __restrict__ WTl,
                 const float* __restrict__ dinv, f16* __restrict__ A, int N) {
    constexpr int NCB = M / 16;
    int wv = threadIdx.x >> 6, l = threadIdx.x & 63;
    int r0w = blockIdx.x * 64 + wv * 16;
    int arow = r0w + (l & 15);
    if (arow >= N) arow = N - 1;
    int kb = (l >> 4) * 8;

    bf16x8 ah[4], al[4];
#pragma unroll
    for (int ks = 0; ks < 4; ++ks) {
        ah[ks] = *(const bf16x8*)&Xh[(long)arow * 128 + ks * 32 + kb];
        al[ks] = *(const bf16x8*)&Xl[(long)arow * 128 + ks * 32 + kb];
    }
    f32x4 acc[NCB];
#pragma unroll
    for (int cb = 0; cb < NCB; ++cb) acc[cb] = f32x4{0.f, 0.f, 0.f, 0.f};
#pragma unroll
    for (int ks = 0; ks < 4; ++ks) {
#pragma unroll
        for (int cb = 0; cb < NCB; ++cb) {
            bf16x8 bh = *(const bf16x8*)&WTh[(long)(cb * 16 + (l & 15)) * 128 + ks * 32 + kb];
            bf16x8 bl = *(const bf16x8*)&WTl[(long)(cb * 16 + (l & 15)) * 128 + ks * 32 + kb];
            acc[cb] = __builtin_amdgcn_mfma_f32_16x16x32_bf16(ah[ks], bh, acc[cb], 0, 0, 0);
            acc[cb] = __builtin_amdgcn_mfma_f32_16x16x32_bf16(ah[ks], bl, acc[cb], 0, 0, 0);
            acc[cb] = __builtin_amdgcn_mfma_f32_16x16x32_bf16(al[ks], bh, acc[cb], 0, 0, 0);
        }
    }
    // C/D layout: col = l&15, row = (l>>4)*4 + i   [verified m89]
    int rbase = r0w + (l >> 4) * 4;
    float dv[4];
#pragma unroll
    for (int i = 0; i < 4; ++i) dv[i] = (rbase + i < N) ? dinv[rbase + i] : 0.f;
#pragma unroll
    for (int cb = 0; cb < NCB; ++cb) {
#pragma unroll
        for (int i = 0; i < 4; ++i) {
            int r = rbase + i;
            if (r < N) A[(long)r * M + cb * 16 + (l & 15)] = (f16)(acc[cb][i] * dv[i]);
        }
    }
}

// ---------------- gather + finish (A fp16, 8 ch/thread, high occupancy) ----------------
__global__ __launch_bounds__(256)
void k_gather(const f16* __restrict__ A, const int* __restrict__ off,
              const unsigned short* __restrict__ csr, const float* __restrict__ dinv,
              const float* __restrict__ bias, float* __restrict__ Bf,
              unsigned short* __restrict__ Bh, unsigned short* __restrict__ Bl,
              int N, int M, int lg, int relu, int mode) {
    int t = blockIdx.x * blockDim.x + threadIdx.x;
    int node = t >> lg;
    if (node >= N) return;
    int q = (t & ((1 << lg) - 1)) << 3;   // 8 channels per thread
    const f16* Aq = A + q;

    float acc[8];
    {
        f16x8 v = *(const f16x8*)&Aq[(long)node * M];  // self-loop
#pragma unroll
        for (int c = 0; c < 8; ++c) acc[c] = (float)v[c];
    }
    int j = off[node], j1 = off[node + 1];
    for (; j + 8 <= j1; j += 8) {
        int s0 = csr[j + 0], s1 = csr[j + 1], s2 = csr[j + 2], s3 = csr[j + 3];
        int s4 = csr[j + 4], s5 = csr[j + 5], s6 = csr[j + 6], s7 = csr[j + 7];
        f16x8 v0 = *(const f16x8*)&Aq[(long)s0 * M];
        f16x8 v1 = *(const f16x8*)&Aq[(long)s1 * M];
        f16x8 v2 = *(const f16x8*)&Aq[(long)s2 * M];
        f16x8 v3 = *(const f16x8*)&Aq[(long)s3 * M];
        f16x8 v4 = *(const f16x8*)&Aq[(long)s4 * M];
        f16x8 v5 = *(const f16x8*)&Aq[(long)s5 * M];
        f16x8 v6 = *(const f16x8*)&Aq[(long)s6 * M];
        f16x8 v7 = *(const f16x8*)&Aq[(long)s7 * M];
#pragma unroll
        for (int c = 0; c < 8; ++c)
            acc[c] += ((float)v0[c] + (float)v1[c] + (float)v2[c] + (float)v3[c])
                    + ((float)v4[c] + (float)v5[c] + (float)v6[c] + (float)v7[c]);
    }
    for (; j + 2 <= j1; j += 2) {
        int s0 = csr[j + 0], s1 = csr[j + 1];
        f16x8 v0 = *(const f16x8*)&Aq[(long)s0 * M];
        f16x8 v1 = *(const f16x8*)&Aq[(long)s1 * M];
#pragma unroll
        for (int c = 0; c < 8; ++c) acc[c] += (float)v0[c] + (float)v1[c];
    }
    if (j < j1) {
        int s = csr[j];
        f16x8 v = *(const f16x8*)&Aq[(long)s * M];
#pragma unroll
        for (int c = 0; c < 8; ++c) acc[c] += (float)v[c];
    }

    float sc = dinv[node];
    float4 bb0 = *(const float4*)&bias[q];
    float4 bb1 = *(const float4*)&bias[q + 4];
    float bv[8] = {bb0.x, bb0.y, bb0.z, bb0.w, bb1.x, bb1.y, bb1.z, bb1.w};
#pragma unroll
    for (int c = 0; c < 8; ++c) {
        acc[c] = acc[c] * sc + bv[c];
        if (relu) acc[c] = fmaxf(acc[c], 0.f);
    }
    if (mode == 0) {
        float4 o0 = make_float4(acc[0], acc[1], acc[2], acc[3]);
        float4 o1 = make_float4(acc[4], acc[5], acc[6], acc[7]);
        *(float4*)&Bf[(long)node * M + q] = o0;
        *(float4*)&Bf[(long)node * M + q + 4] = o1;
    } else {
        u16x8 h, lo;
#pragma unroll
        for (int c = 0; c < 8; ++c) {
            unsigned short hh = f2bf_rne(acc[c]);
            h[c] = hh;
            lo[c] = f2bf_rne(acc[c] - bf2f(hh));
        }
        *(u16x8*)&Bh[(long)node * M + q] = h;
        *(u16x8*)&Bl[(long)node * M + q] = lo;
    }
}

// ---------------- decode: out[i] = dot64(z[a], z[b]) ----------------
__global__ void k_decode(const float* __restrict__ z, const int* __restrict__ eli,
                         float* __restrict__ out, int L) {
    int t = blockIdx.x * blockDim.x + threadIdx.x;
    int e = t >> 4;
    int lane = t & 15;
    if (e >= L) return;
    int a = eli[e], b = eli[L + e];
    float4 va = *(const float4*)&z[(long)a * 64 + lane * 4];
    float4 vb = *(const float4*)&z[(long)b * 64 + lane * 4];
    float s = va.x * vb.x + va.y * vb.y + va.z * vb.z + va.w * vb.w;
    s += __shfl_xor(s, 1, 16);
    s += __shfl_xor(s, 2, 16);
    s += __shfl_xor(s, 4, 16);
    s += __shfl_xor(s, 8, 16);
    if (lane == 0) out[e] = s;
}

extern "C" void kernel_launch(void* const* d_in, const int* in_sizes, int n_in,
                              void* d_out, int out_size, void* d_ws, size_t ws_size,
                              hipStream_t stream) {
    const float* x   = (const float*)d_in[0];
    const float* W1  = (const float*)d_in[1];
    const float* b1  = (const float*)d_in[2];
    const float* W2  = (const float*)d_in[3];
    const float* b2  = (const float*)d_in[4];
    const float* W3  = (const float*)d_in[5];
    const float* b3  = (const float*)d_in[6];
    const int*   ei  = (const int*)d_in[7];
    const int*   eli = (const int*)d_in[8];
    float* out = (float*)d_out;

    char* ws = (char*)d_ws;
    float* dinv = (float*)ws;                  ws += 50048 * 4;
    f16*   A    = (f16*)ws;                    ws += (long)N_NODES * 128 * 2;
    float* z    = (float*)ws;                  ws += (long)N_NODES * 64 * 4;
    unsigned short* inh = (unsigned short*)ws; ws += (long)N_NODES * 128 * 2;
    unsigned short* inl = (unsigned short*)ws; ws += (long)N_NODES * 128 * 2;
    int*   cnt  = (int*)ws;                    ws += 50048 * 4;
    int*   cnt2 = (int*)ws;                    ws += 50048 * 4;   // contiguous with cnt
    int*   off  = (int*)ws;                    ws += 50048 * 4;
    unsigned short* csr = (unsigned short*)ws; ws += (long)N_EDGES * 2;
    int*   bsum = (int*)ws;                    ws += 256 * 4;
    unsigned short* WT1h = (unsigned short*)ws; ws += 16384 * 2;
    unsigned short* WT1l = (unsigned short*)ws; ws += 16384 * 2;
    unsigned short* WT2h = (unsigned short*)ws; ws += 16384 * 2;
    unsigned short* WT2l = (unsigned short*)ws; ws += 16384 * 2;
    unsigned short* WT3h = (unsigned short*)ws; ws += 8192 * 2;
    unsigned short* WT3l = (unsigned short*)ws; ws += 8192 * 2;

    const int* esrc = ei;
    const int* edst = ei + N_EDGES;

    const int NB = (N_NODES + 255) / 256;  // 196

    // zero cnt+cnt2, then prep (xprep | wprep | deg), scan chain
    hipMemsetAsync(cnt, 0, 2 * 50048 * sizeof(int), stream);
    k_prep   <<<9439, 256, 0, stream>>>(x, inh, inl, W1, W2, W3,
                                        WT1h, WT1l, WT2h, WT2l, WT3h, WT3l, edst, cnt);
    k_partial<<<NB, 256, 0, stream>>>(cnt, dinv, bsum, N_NODES);
    k_offsets<<<NB, 256, 0, stream>>>(cnt, bsum, off, N_NODES, NB);

    // standalone XCD-partitioned bucket fill (isolated from streaming traffic)
    k_bucket<<<25000, 256, 0, stream>>>(esrc, edst, off, cnt2, csr);

    const int ga128 = (N_NODES * 16 + 255) / 256;   // 16 thr/node
    const int ga64  = (N_NODES * 8 + 255) / 256;    // 8 thr/node

    // layer 1
    k_gemm_mfma<128><<<GEMM_BLOCKS, 256, 0, stream>>>(inh, inl, WT1h, WT1l, dinv, A, N_NODES);
    k_gather<<<ga128, 256, 0, stream>>>(A, off, csr, dinv, b1, nullptr, inh, inl,
                                        N_NODES, 128, 4, 1, 1);
    // layer 2
    k_gemm_mfma<128><<<GEMM_BLOCKS, 256, 0, stream>>>(inh, inl, WT2h, WT2l, dinv, A, N_NODES);
    k_gather<<<ga128, 256, 0, stream>>>(A, off, csr, dinv, b2, nullptr, inh, inl,
                                        N_NODES, 128, 4, 1, 1);
    // layer 3 (M=64, no relu, fp32 out)
    k_gemm_mfma<64><<<GEMM_BLOCKS, 256, 0, stream>>>(inh, inl, WT3h, WT3l, dinv, A, N_NODES);
    k_gather<<<ga64, 256, 0, stream>>>(A, off, csr, dinv, b3, z, nullptr, nullptr,
                                       N_NODES, 64, 3, 0, 0);

    // decode
    k_decode<<<(N_LABEL * 16 + 255) / 256, 256, 0, stream>>>(z, eli, out, N_LABEL);
}

// Round 10
// 284.240 us; speedup vs baseline: 1.2722x; 1.0234x over previous
//
#include <hip/hip_runtime.h>

#define N_NODES 50000
#define N_EDGES 800000
#define N_LABEL 200000
#define GEMM_BLOCKS 782   // ceil(50000/64)

typedef __attribute__((ext_vector_type(4))) float f32x4;
typedef _Float16 f16;
typedef __attribute__((ext_vector_type(8))) _Float16 f16x8;

// ---------------- prep: W transpose/split fp16 hi+lo | deg_count ----------------
// blocks [0,64): wprep; [64,3189): deg_count (cnt pre-zeroed by memset)
__global__ __launch_bounds__(256)
void k_prep(const float* __restrict__ W1, const float* __restrict__ W2,
            const float* __restrict__ W3,
            f16* WT1h, f16* WT1l, f16* WT2h, f16* WT2l, f16* WT3h, f16* WT3l,
            const int* __restrict__ dst, int* cnt) {
    int b = blockIdx.x, tid = threadIdx.x;
    if (b < 64) {
        int t = b * 256 + tid;                 // < 16384
        int c = t >> 7, k = t & 127;
        float w = W1[k * 128 + c];
        f16 h = (f16)w;
        WT1h[c * 128 + k] = h; WT1l[c * 128 + k] = (f16)(w - (float)h);
        w = W2[k * 128 + c];
        h = (f16)w;
        WT2h[c * 128 + k] = h; WT2l[c * 128 + k] = (f16)(w - (float)h);
        if (c < 64) {
            w = W3[k * 64 + c];
            h = (f16)w;
            WT3h[c * 128 + k] = h; WT3l[c * 128 + k] = (f16)(w - (float)h);
        }
    } else {
        int i = (b - 64) * 256 + tid;          // < 800,000 exactly
        atomicAdd(&cnt[dst[i]], 1);
    }
}

// ---------------- scan chain ----------------
__global__ __launch_bounds__(256)
void k_partial(const int* __restrict__ cnt, float* __restrict__ dinv,
               int* __restrict__ bsum, int N) {
    __shared__ int wsum[4];
    int b = blockIdx.x, t = threadIdx.x;
    int i = b * 256 + t;
    int v = (i < N) ? cnt[i] : 0;
    if (i < N) dinv[i] = rsqrtf((float)v + 1.0f);
    int s = v;
#pragma unroll
    for (int d = 1; d < 64; d <<= 1) s += __shfl_xor(s, d, 64);
    if ((t & 63) == 0) wsum[t >> 6] = s;
    __syncthreads();
    if (t == 0) bsum[b] = wsum[0] + wsum[1] + wsum[2] + wsum[3];
}

__global__ __launch_bounds__(256)
void k_offsets(const int* __restrict__ cnt, const int* __restrict__ bsum,
               int* __restrict__ off, int N, int NB) {
    __shared__ int wsum[4];
    __shared__ int add0_s;
    int b = blockIdx.x, t = threadIdx.x;
    int v0 = (t < b && t < NB) ? bsum[t] : 0;
    int s0 = v0;
#pragma unroll
    for (int d = 1; d < 64; d <<= 1) s0 += __shfl_xor(s0, d, 64);
    if ((t & 63) == 0) wsum[t >> 6] = s0;
    __syncthreads();
    if (t == 0) add0_s = wsum[0] + wsum[1] + wsum[2] + wsum[3];
    __syncthreads();
    int add = add0_s;
    __syncthreads();
    int i = b * 256 + t;
    int v = (i < N) ? cnt[i] : 0;
    int lane = t & 63, w = t >> 6;
    int sv = v;
#pragma unroll
    for (int d = 1; d < 64; d <<= 1) {
        int u = __shfl_up(sv, d, 64);
        if (lane >= d) sv += u;
    }
    if (lane == 63) wsum[w] = sv;
    __syncthreads();
    for (int ww = 0; ww < w; ++ww) add += wsum[ww];
    if (i < N) off[i + 1] = add + sv;
    if (i == 0) off[0] = 0;
}

// ---------------- XCD-partitioned bucket fill (standalone — R8 lesson) ----------------
__global__ __launch_bounds__(256)
void k_bucket(const int* __restrict__ srcv, const int* __restrict__ dstv,
              const int* __restrict__ off, int* cnt2, unsigned short* __restrict__ csr) {
    int vb = blockIdx.x;
    int g = vb & 7;
    int i = (vb >> 3) * 256 + threadIdx.x;   // < 800,000 exactly
    int d = dstv[i];
    if ((unsigned)(d - g * 6250) < 6250u) {
        int slot = off[d] + atomicAdd(&cnt2[d], 1);
        csr[slot] = (unsigned short)srcv[i];
    }
}

// ---------------- GEMM layer 1: reads fp32 x, splits fp16 hi/lo in-register ----------------
// A[r][c] = fp16((x@W1)[r][c] * dinv[r]);  3 MFMAs: xh·Wh + xh·Wl + xl·Wh
__global__ __launch_bounds__(256)
void k_gemm1(const float* __restrict__ x,
             const f16* __restrict__ WTh, const f16* __restrict__ WTl,
             const float* __restrict__ dinv, f16* __restrict__ A, int N) {
    constexpr int M = 128, NCB = 8;
    int wv = threadIdx.x >> 6, l = threadIdx.x & 63;
    int r0w = blockIdx.x * 64 + wv * 16;
    int arow = r0w + (l & 15);
    if (arow >= N) arow = N - 1;
    int kb = (l >> 4) * 8;

    f16x8 ah[4], al[4];
#pragma unroll
    for (int ks = 0; ks < 4; ++ks) {
        const float* xp = &x[(long)arow * 128 + ks * 32 + kb];
        float4 a0 = *(const float4*)xp;
        float4 a1 = *(const float4*)(xp + 4);
        float fv[8] = {a0.x, a0.y, a0.z, a0.w, a1.x, a1.y, a1.z, a1.w};
#pragma unroll
        for (int j = 0; j < 8; ++j) {
            f16 h = (f16)fv[j];
            ah[ks][j] = h;
            al[ks][j] = (f16)(fv[j] - (float)h);
        }
    }
    f32x4 acc[NCB];
#pragma unroll
    for (int cb = 0; cb < NCB; ++cb) acc[cb] = f32x4{0.f, 0.f, 0.f, 0.f};
#pragma unroll
    for (int ks = 0; ks < 4; ++ks) {
#pragma unroll
        for (int cb = 0; cb < NCB; ++cb) {
            f16x8 bh = *(const f16x8*)&WTh[(long)(cb * 16 + (l & 15)) * 128 + ks * 32 + kb];
            f16x8 bl = *(const f16x8*)&WTl[(long)(cb * 16 + (l & 15)) * 128 + ks * 32 + kb];
            acc[cb] = __builtin_amdgcn_mfma_f32_16x16x32_f16(ah[ks], bh, acc[cb], 0, 0, 0);
            acc[cb] = __builtin_amdgcn_mfma_f32_16x16x32_f16(ah[ks], bl, acc[cb], 0, 0, 0);
            acc[cb] = __builtin_amdgcn_mfma_f32_16x16x32_f16(al[ks], bh, acc[cb], 0, 0, 0);
        }
    }
    // C/D layout: col = l&15, row = (l>>4)*4 + i   [verified m89]
    int rbase = r0w + (l >> 4) * 4;
    float dv[4];
#pragma unroll
    for (int i = 0; i < 4; ++i) dv[i] = (rbase + i < N) ? dinv[rbase + i] : 0.f;
#pragma unroll
    for (int cb = 0; cb < NCB; ++cb) {
#pragma unroll
        for (int i = 0; i < 4; ++i) {
            int r = rbase + i;
            if (r < N) A[(long)r * M + cb * 16 + (l & 15)] = (f16)(acc[cb][i] * dv[i]);
        }
    }
}

// ---------------- GEMM layers 2/3: B fp16 exact, 2 MFMAs (B·Wh + B·Wl) ----------------
template<int M>
__global__ __launch_bounds__(256)
void k_gemm23(const f16* __restrict__ B,
              const f16* __restrict__ WTh, const f16* __restrict__ WTl,
              const float* __restrict__ dinv, f16* __restrict__ A, int N) {
    constexpr int NCB = M / 16;
    int wv = threadIdx.x >> 6, l = threadIdx.x & 63;
    int r0w = blockIdx.x * 64 + wv * 16;
    int arow = r0w + (l & 15);
    if (arow >= N) arow = N - 1;
    int kb = (l >> 4) * 8;

    f16x8 a[4];
#pragma unroll
    for (int ks = 0; ks < 4; ++ks)
        a[ks] = *(const f16x8*)&B[(long)arow * 128 + ks * 32 + kb];

    f32x4 acc[NCB];
#pragma unroll
    for (int cb = 0; cb < NCB; ++cb) acc[cb] = f32x4{0.f, 0.f, 0.f, 0.f};
#pragma unroll
    for (int ks = 0; ks < 4; ++ks) {
#pragma unroll
        for (int cb = 0; cb < NCB; ++cb) {
            f16x8 bh = *(const f16x8*)&WTh[(long)(cb * 16 + (l & 15)) * 128 + ks * 32 + kb];
            f16x8 bl = *(const f16x8*)&WTl[(long)(cb * 16 + (l & 15)) * 128 + ks * 32 + kb];
            acc[cb] = __builtin_amdgcn_mfma_f32_16x16x32_f16(a[ks], bh, acc[cb], 0, 0, 0);
            acc[cb] = __builtin_amdgcn_mfma_f32_16x16x32_f16(a[ks], bl, acc[cb], 0, 0, 0);
        }
    }
    int rbase = r0w + (l >> 4) * 4;
    float dv[4];
#pragma unroll
    for (int i = 0; i < 4; ++i) dv[i] = (rbase + i < N) ? dinv[rbase + i] : 0.f;
#pragma unroll
    for (int cb = 0; cb < NCB; ++cb) {
#pragma unroll
        for (int i = 0; i < 4; ++i) {
            int r = rbase + i;
            if (r < N) A[(long)r * M + cb * 16 + (l & 15)] = (f16)(acc[cb][i] * dv[i]);
        }
    }
}

// ---------------- gather + finish (A fp16, 8 ch/thread) ----------------
// mode 0: write fp32 Bf;  mode 1: write fp16 Bo
__global__ __launch_bounds__(256)
void k_gather(const f16* __restrict__ A, const int* __restrict__ off,
              const unsigned short* __restrict__ csr, const float* __restrict__ dinv,
              const float* __restrict__ bias, float* __restrict__ Bf,
              f16* __restrict__ Bo,
              int N, int M, int lg, int relu, int mode) {
    int t = blockIdx.x * blockDim.x + threadIdx.x;
    int node = t >> lg;
    if (node >= N) return;
    int q = (t & ((1 << lg) - 1)) << 3;   // 8 channels per thread
    const f16* Aq = A + q;

    float acc[8];
    {
        f16x8 v = *(const f16x8*)&Aq[(long)node * M];  // self-loop
#pragma unroll
        for (int c = 0; c < 8; ++c) acc[c] = (float)v[c];
    }
    int j = off[node], j1 = off[node + 1];
    for (; j + 8 <= j1; j += 8) {
        int s0 = csr[j + 0], s1 = csr[j + 1], s2 = csr[j + 2], s3 = csr[j + 3];
        int s4 = csr[j + 4], s5 = csr[j + 5], s6 = csr[j + 6], s7 = csr[j + 7];
        f16x8 v0 = *(const f16x8*)&Aq[(long)s0 * M];
        f16x8 v1 = *(const f16x8*)&Aq[(long)s1 * M];
        f16x8 v2 = *(const f16x8*)&Aq[(long)s2 * M];
        f16x8 v3 = *(const f16x8*)&Aq[(long)s3 * M];
        f16x8 v4 = *(const f16x8*)&Aq[(long)s4 * M];
        f16x8 v5 = *(const f16x8*)&Aq[(long)s5 * M];
        f16x8 v6 = *(const f16x8*)&Aq[(long)s6 * M];
        f16x8 v7 = *(const f16x8*)&Aq[(long)s7 * M];
#pragma unroll
        for (int c = 0; c < 8; ++c)
            acc[c] += ((float)v0[c] + (float)v1[c] + (float)v2[c] + (float)v3[c])
                    + ((float)v4[c] + (float)v5[c] + (float)v6[c] + (float)v7[c]);
    }
    for (; j + 2 <= j1; j += 2) {
        int s0 = csr[j + 0], s1 = csr[j + 1];
        f16x8 v0 = *(const f16x8*)&Aq[(long)s0 * M];
        f16x8 v1 = *(const f16x8*)&Aq[(long)s1 * M];
#pragma unroll
        for (int c = 0; c < 8; ++c) acc[c] += (float)v0[c] + (float)v1[c];
    }
    if (j < j1) {
        int s = csr[j];
        f16x8 v = *(const f16x8*)&Aq[(long)s * M];
#pragma unroll
        for (int c = 0; c < 8; ++c) acc[c] += (float)v[c];
    }

    float sc = dinv[node];
    float4 bb0 = *(const float4*)&bias[q];
    float4 bb1 = *(const float4*)&bias[q + 4];
    float bv[8] = {bb0.x, bb0.y, bb0.z, bb0.w, bb1.x, bb1.y, bb1.z, bb1.w};
#pragma unroll
    for (int c = 0; c < 8; ++c) {
        acc[c] = acc[c] * sc + bv[c];
        if (relu) acc[c] = fmaxf(acc[c], 0.f);
    }
    if (mode == 0) {
        float4 o0 = make_float4(acc[0], acc[1], acc[2], acc[3]);
        float4 o1 = make_float4(acc[4], acc[5], acc[6], acc[7]);
        *(float4*)&Bf[(long)node * M + q] = o0;
        *(float4*)&Bf[(long)node * M + q + 4] = o1;
    } else {
        f16x8 o;
#pragma unroll
        for (int c = 0; c < 8; ++c) o[c] = (f16)acc[c];
        *(f16x8*)&Bo[(long)node * M + q] = o;
    }
}

// ---------------- decode: out[i] = dot64(z[a], z[b]) ----------------
__global__ void k_decode(const float* __restrict__ z, const int* __restrict__ eli,
                         float* __restrict__ out, int L) {
    int t = blockIdx.x * blockDim.x + threadIdx.x;
    int e = t >> 4;
    int lane = t & 15;
    if (e >= L) return;
    int a = eli[e], b = eli[L + e];
    float4 va = *(const float4*)&z[(long)a * 64 + lane * 4];
    float4 vb = *(const float4*)&z[(long)b * 64 + lane * 4];
    float s = va.x * vb.x + va.y * vb.y + va.z * vb.z + va.w * vb.w;
    s += __shfl_xor(s, 1, 16);
    s += __shfl_xor(s, 2, 16);
    s += __shfl_xor(s, 4, 16);
    s += __shfl_xor(s, 8, 16);
    if (lane == 0) out[e] = s;
}

extern "C" void kernel_launch(void* const* d_in, const int* in_sizes, int n_in,
                              void* d_out, int out_size, void* d_ws, size_t ws_size,
                              hipStream_t stream) {
    const float* x   = (const float*)d_in[0];
    const float* W1  = (const float*)d_in[1];
    const float* b1  = (const float*)d_in[2];
    const float* W2  = (const float*)d_in[3];
    const float* b2  = (const float*)d_in[4];
    const float* W3  = (const float*)d_in[5];
    const float* b3  = (const float*)d_in[6];
    const int*   ei  = (const int*)d_in[7];
    const int*   eli = (const int*)d_in[8];
    float* out = (float*)d_out;

    char* ws = (char*)d_ws;
    float* dinv = (float*)ws;                  ws += 50048 * 4;
    f16*   A    = (f16*)ws;                    ws += (long)N_NODES * 128 * 2;
    f16*   B    = (f16*)ws;                    ws += (long)N_NODES * 128 * 2;
    float* z    = (float*)ws;                  ws += (long)N_NODES * 64 * 4;
    int*   cnt  = (int*)ws;                    ws += 50048 * 4;
    int*   cnt2 = (int*)ws;                    ws += 50048 * 4;   // contiguous with cnt
    int*   off  = (int*)ws;                    ws += 50048 * 4;
    unsigned short* csr = (unsigned short*)ws; ws += (long)N_EDGES * 2;
    int*   bsum = (int*)ws;                    ws += 256 * 4;
    f16*   WT1h = (f16*)ws;                    ws += 16384 * 2;
    f16*   WT1l = (f16*)ws;                    ws += 16384 * 2;
    f16*   WT2h = (f16*)ws;                    ws += 16384 * 2;
    f16*   WT2l = (f16*)ws;                    ws += 16384 * 2;
    f16*   WT3h = (f16*)ws;                    ws += 8192 * 2;
    f16*   WT3l = (f16*)ws;                    ws += 8192 * 2;

    const int* esrc = ei;
    const int* edst = ei + N_EDGES;

    const int NB = (N_NODES + 255) / 256;  // 196

    hipMemsetAsync(cnt, 0, 2 * 50048 * sizeof(int), stream);
    k_prep   <<<3189, 256, 0, stream>>>(W1, W2, W3, WT1h, WT1l, WT2h, WT2l,
                                        WT3h, WT3l, edst, cnt);
    k_partial<<<NB, 256, 0, stream>>>(cnt, dinv, bsum, N_NODES);
    k_offsets<<<NB, 256, 0, stream>>>(cnt, bsum, off, N_NODES, NB);
    k_bucket <<<25000, 256, 0, stream>>>(esrc, edst, off, cnt2, csr);

    const int ga128 = (N_NODES * 16 + 255) / 256;   // 16 thr/node
    const int ga64  = (N_NODES * 8 + 255) / 256;    // 8 thr/node

    // layer 1 (x fp32 -> in-register fp16 split)
    k_gemm1<<<GEMM_BLOCKS, 256, 0, stream>>>(x, WT1h, WT1l, dinv, A, N_NODES);
    k_gather<<<ga128, 256, 0, stream>>>(A, off, csr, dinv, b1, nullptr, B,
                                        N_NODES, 128, 4, 1, 1);
    // layer 2
    k_gemm23<128><<<GEMM_BLOCKS, 256, 0, stream>>>(B, WT2h, WT2l, dinv, A, N_NODES);
    k_gather<<<ga128, 256, 0, stream>>>(A, off, csr, dinv, b2, nullptr, B,
                                        N_NODES, 128, 4, 1, 1);
    // layer 3 (M=64, no relu, fp32 out)
    k_gemm23<64><<<GEMM_BLOCKS, 256, 0, stream>>>(B, WT3h, WT3l, dinv, A, N_NODES);
    k_gather<<<ga64, 256, 0, stream>>>(A, off, csr, dinv, b3, z, nullptr,
                                       N_NODES, 64, 3, 0, 0);

    // decode
    k_decode<<<(N_LABEL * 16 + 255) / 256, 256, 0, stream>>>(z, eli, out, N_LABEL);
}

// Round 11
// 269.818 us; speedup vs baseline: 1.3402x; 1.0535x over previous
//
#include <hip/hip_runtime.h>

#define N_NODES 50000
#define N_EDGES 800000
#define N_LABEL 200000
#define ROW_BLOCKS 782   // ceil(50000/64)

typedef __attribute__((ext_vector_type(4))) float f32x4;
typedef _Float16 f16;
typedef __attribute__((ext_vector_type(8))) _Float16 f16x8;

// ---------------- zero cnt+cnt2 (replaces pathological hipMemsetAsync) ----------------
__global__ __launch_bounds__(256)
void k_zero(int4* __restrict__ p, int n4) {
    int i = blockIdx.x * 256 + threadIdx.x;
    if (i < n4) p[i] = int4{0, 0, 0, 0};
}

// ---------------- prep: W transpose/split fp16 hi+lo | XCD-partitioned deg_count ----------
// blocks [0,64): wprep; [64, 64+25000): partitioned deg (group g=vb&7 owns dst range)
__global__ __launch_bounds__(256)
void k_prep(const float* __restrict__ W1, const float* __restrict__ W2,
            const float* __restrict__ W3,
            f16* WT1h, f16* WT1l, f16* WT2h, f16* WT2l, f16* WT3h, f16* WT3l,
            const int* __restrict__ dst, int* cnt) {
    int b = blockIdx.x, tid = threadIdx.x;
    if (b < 64) {
        int t = b * 256 + tid;                 // < 16384
        int c = t >> 7, k = t & 127;
        float w = W1[k * 128 + c];
        f16 h = (f16)w;
        WT1h[c * 128 + k] = h; WT1l[c * 128 + k] = (f16)(w - (float)h);
        w = W2[k * 128 + c];
        h = (f16)w;
        WT2h[c * 128 + k] = h; WT2l[c * 128 + k] = (f16)(w - (float)h);
        if (c < 64) {
            w = W3[k * 64 + c];
            h = (f16)w;
            WT3h[c * 128 + k] = h; WT3l[c * 128 + k] = (f16)(w - (float)h);
        }
    } else {
        int vb = b - 64;                       // [0, 25000)
        int g = vb & 7;
        int i = (vb >> 3) * 256 + tid;         // < 800,000 exactly
        int d = dst[i];
        if ((unsigned)(d - g * 6250) < 6250u) atomicAdd(&cnt[d], 1);
    }
}

// ---------------- scan chain ----------------
__global__ __launch_bounds__(256)
void k_partial(const int* __restrict__ cnt, float* __restrict__ dinv,
               int* __restrict__ bsum, int N) {
    __shared__ int wsum[4];
    int b = blockIdx.x, t = threadIdx.x;
    int i = b * 256 + t;
    int v = (i < N) ? cnt[i] : 0;
    if (i < N) dinv[i] = rsqrtf((float)v + 1.0f);
    int s = v;
#pragma unroll
    for (int d = 1; d < 64; d <<= 1) s += __shfl_xor(s, d, 64);
    if ((t & 63) == 0) wsum[t >> 6] = s;
    __syncthreads();
    if (t == 0) bsum[b] = wsum[0] + wsum[1] + wsum[2] + wsum[3];
}

__global__ __launch_bounds__(256)
void k_offsets(const int* __restrict__ cnt, const int* __restrict__ bsum,
               int* __restrict__ off, int N, int NB) {
    __shared__ int wsum[4];
    __shared__ int add0_s;
    int b = blockIdx.x, t = threadIdx.x;
    int v0 = (t < b && t < NB) ? bsum[t] : 0;
    int s0 = v0;
#pragma unroll
    for (int d = 1; d < 64; d <<= 1) s0 += __shfl_xor(s0, d, 64);
    if ((t & 63) == 0) wsum[t >> 6] = s0;
    __syncthreads();
    if (t == 0) add0_s = wsum[0] + wsum[1] + wsum[2] + wsum[3];
    __syncthreads();
    int add = add0_s;
    __syncthreads();
    int i = b * 256 + t;
    int v = (i < N) ? cnt[i] : 0;
    int lane = t & 63, w = t >> 6;
    int sv = v;
#pragma unroll
    for (int d = 1; d < 64; d <<= 1) {
        int u = __shfl_up(sv, d, 64);
        if (lane >= d) sv += u;
    }
    if (lane == 63) wsum[w] = sv;
    __syncthreads();
    for (int ww = 0; ww < w; ++ww) add += wsum[ww];
    if (i < N) off[i + 1] = add + sv;
    if (i == 0) off[0] = 0;
}

// ---------------- XCD-partitioned bucket fill ----------------
__global__ __launch_bounds__(256)
void k_bucket(const int* __restrict__ srcv, const int* __restrict__ dstv,
              const int* __restrict__ off, int* cnt2, unsigned short* __restrict__ csr) {
    int vb = blockIdx.x;
    int g = vb & 7;
    int i = (vb >> 3) * 256 + threadIdx.x;   // < 800,000 exactly
    int d = dstv[i];
    if ((unsigned)(d - g * 6250) < 6250u) {
        int slot = off[d] + atomicAdd(&cnt2[d], 1);
        csr[slot] = (unsigned short)srcv[i];
    }
}

// ---------------- GEMM layer 1: fp32 x, in-register fp16 split, 2-way col split ----------
// grid = ROW_BLOCKS*2; block b: rows (b>>1)*64.., cols (b&1)*64..+64 (NCB=4)
__global__ __launch_bounds__(256)
void k_gemm1(const float* __restrict__ x,
             const f16* __restrict__ WTh, const f16* __restrict__ WTl,
             const float* __restrict__ dinv, f16* __restrict__ A, int N) {
    constexpr int M = 128, NCB = 4;
    int b = blockIdx.x;
    int c0 = (b & 1) * 64;
    int wv = threadIdx.x >> 6, l = threadIdx.x & 63;
    int r0w = (b >> 1) * 64 + wv * 16;
    int arow = r0w + (l & 15);
    if (arow >= N) arow = N - 1;
    int kb = (l >> 4) * 8;

    f16x8 ah[4], al[4];
#pragma unroll
    for (int ks = 0; ks < 4; ++ks) {
        const float* xp = &x[(long)arow * 128 + ks * 32 + kb];
        float4 a0 = *(const float4*)xp;
        float4 a1 = *(const float4*)(xp + 4);
        float fv[8] = {a0.x, a0.y, a0.z, a0.w, a1.x, a1.y, a1.z, a1.w};
#pragma unroll
        for (int j = 0; j < 8; ++j) {
            f16 h = (f16)fv[j];
            ah[ks][j] = h;
            al[ks][j] = (f16)(fv[j] - (float)h);
        }
    }
    f32x4 acc[NCB];
#pragma unroll
    for (int cb = 0; cb < NCB; ++cb) acc[cb] = f32x4{0.f, 0.f, 0.f, 0.f};
#pragma unroll
    for (int ks = 0; ks < 4; ++ks) {
#pragma unroll
        for (int cb = 0; cb < NCB; ++cb) {
            long wi = (long)(c0 + cb * 16 + (l & 15)) * 128 + ks * 32 + kb;
            f16x8 bh = *(const f16x8*)&WTh[wi];
            f16x8 bl = *(const f16x8*)&WTl[wi];
            acc[cb] = __builtin_amdgcn_mfma_f32_16x16x32_f16(ah[ks], bh, acc[cb], 0, 0, 0);
            acc[cb] = __builtin_amdgcn_mfma_f32_16x16x32_f16(ah[ks], bl, acc[cb], 0, 0, 0);
            acc[cb] = __builtin_amdgcn_mfma_f32_16x16x32_f16(al[ks], bh, acc[cb], 0, 0, 0);
        }
    }
    // C/D layout: col = l&15, row = (l>>4)*4 + i   [verified m89]
    int rbase = r0w + (l >> 4) * 4;
    float dv[4];
#pragma unroll
    for (int i = 0; i < 4; ++i) dv[i] = (rbase + i < N) ? dinv[rbase + i] : 0.f;
#pragma unroll
    for (int cb = 0; cb < NCB; ++cb) {
#pragma unroll
        for (int i = 0; i < 4; ++i) {
            int r = rbase + i;
            if (r < N) A[(long)r * M + c0 + cb * 16 + (l & 15)] = (f16)(acc[cb][i] * dv[i]);
        }
    }
}

// ---------------- GEMM layers 2/3: B fp16 exact, 2 MFMAs, 2-way col split ----------------
// grid = ROW_BLOCKS*2; NCB = M/32
template<int M>
__global__ __launch_bounds__(256)
void k_gemm23(const f16* __restrict__ B,
              const f16* __restrict__ WTh, const f16* __restrict__ WTl,
              const float* __restrict__ dinv, f16* __restrict__ A, int N) {
    constexpr int NCB = M / 32;
    int b = blockIdx.x;
    int c0 = (b & 1) * (M / 2);
    int wv = threadIdx.x >> 6, l = threadIdx.x & 63;
    int r0w = (b >> 1) * 64 + wv * 16;
    int arow = r0w + (l & 15);
    if (arow >= N) arow = N - 1;
    int kb = (l >> 4) * 8;

    f16x8 a[4];
#pragma unroll
    for (int ks = 0; ks < 4; ++ks)
        a[ks] = *(const f16x8*)&B[(long)arow * 128 + ks * 32 + kb];

    f32x4 acc[NCB];
#pragma unroll
    for (int cb = 0; cb < NCB; ++cb) acc[cb] = f32x4{0.f, 0.f, 0.f, 0.f};
#pragma unroll
    for (int ks = 0; ks < 4; ++ks) {
#pragma unroll
        for (int cb = 0; cb < NCB; ++cb) {
            long wi = (long)(c0 + cb * 16 + (l & 15)) * 128 + ks * 32 + kb;
            f16x8 bh = *(const f16x8*)&WTh[wi];
            f16x8 bl = *(const f16x8*)&WTl[wi];
            acc[cb] = __builtin_amdgcn_mfma_f32_16x16x32_f16(a[ks], bh, acc[cb], 0, 0, 0);
            acc[cb] = __builtin_amdgcn_mfma_f32_16x16x32_f16(a[ks], bl, acc[cb], 0, 0, 0);
        }
    }
    int rbase = r0w + (l >> 4) * 4;
    float dv[4];
#pragma unroll
    for (int i = 0; i < 4; ++i) dv[i] = (rbase + i < N) ? dinv[rbase + i] : 0.f;
#pragma unroll
    for (int cb = 0; cb < NCB; ++cb) {
#pragma unroll
        for (int i = 0; i < 4; ++i) {
            int r = rbase + i;
            if (r < N) A[(long)r * M + c0 + cb * 16 + (l & 15)] = (f16)(acc[cb][i] * dv[i]);
        }
    }
}

// ---------------- gather + finish (A fp16, 8 ch/thread) ----------------
// mode 0: write fp32 Bf;  mode 1: write fp16 Bo
__global__ __launch_bounds__(256)
void k_gather(const f16* __restrict__ A, const int* __restrict__ off,
              const unsigned short* __restrict__ csr, const float* __restrict__ dinv,
              const float* __restrict__ bias, float* __restrict__ Bf,
              f16* __restrict__ Bo,
              int N, int M, int lg, int relu, int mode) {
    int t = blockIdx.x * blockDim.x + threadIdx.x;
    int node = t >> lg;
    if (node >= N) return;
    int q = (t & ((1 << lg) - 1)) << 3;   // 8 channels per thread
    const f16* Aq = A + q;

    float acc[8];
    {
        f16x8 v = *(const f16x8*)&Aq[(long)node * M];  // self-loop
#pragma unroll
        for (int c = 0; c < 8; ++c) acc[c] = (float)v[c];
    }
    int j = off[node], j1 = off[node + 1];
    for (; j + 8 <= j1; j += 8) {
        int s0 = csr[j + 0], s1 = csr[j + 1], s2 = csr[j + 2], s3 = csr[j + 3];
        int s4 = csr[j + 4], s5 = csr[j + 5], s6 = csr[j + 6], s7 = csr[j + 7];
        f16x8 v0 = *(const f16x8*)&Aq[(long)s0 * M];
        f16x8 v1 = *(const f16x8*)&Aq[(long)s1 * M];
        f16x8 v2 = *(const f16x8*)&Aq[(long)s2 * M];
        f16x8 v3 = *(const f16x8*)&Aq[(long)s3 * M];
        f16x8 v4 = *(const f16x8*)&Aq[(long)s4 * M];
        f16x8 v5 = *(const f16x8*)&Aq[(long)s5 * M];
        f16x8 v6 = *(const f16x8*)&Aq[(long)s6 * M];
        f16x8 v7 = *(const f16x8*)&Aq[(long)s7 * M];
#pragma unroll
        for (int c = 0; c < 8; ++c)
            acc[c] += ((float)v0[c] + (float)v1[c] + (float)v2[c] + (float)v3[c])
                    + ((float)v4[c] + (float)v5[c] + (float)v6[c] + (float)v7[c]);
    }
    for (; j + 2 <= j1; j += 2) {
        int s0 = csr[j + 0], s1 = csr[j + 1];
        f16x8 v0 = *(const f16x8*)&Aq[(long)s0 * M];
        f16x8 v1 = *(const f16x8*)&Aq[(long)s1 * M];
#pragma unroll
        for (int c = 0; c < 8; ++c) acc[c] += (float)v0[c] + (float)v1[c];
    }
    if (j < j1) {
        int s = csr[j];
        f16x8 v = *(const f16x8*)&Aq[(long)s * M];
#pragma unroll
        for (int c = 0; c < 8; ++c) acc[c] += (float)v[c];
    }

    float sc = dinv[node];
    float4 bb0 = *(const float4*)&bias[q];
    float4 bb1 = *(const float4*)&bias[q + 4];
    float bv[8] = {bb0.x, bb0.y, bb0.z, bb0.w, bb1.x, bb1.y, bb1.z, bb1.w};
#pragma unroll
    for (int c = 0; c < 8; ++c) {
        acc[c] = acc[c] * sc + bv[c];
        if (relu) acc[c] = fmaxf(acc[c], 0.f);
    }
    if (mode == 0) {
        float4 o0 = make_float4(acc[0], acc[1], acc[2], acc[3]);
        float4 o1 = make_float4(acc[4], acc[5], acc[6], acc[7]);
        *(float4*)&Bf[(long)node * M + q] = o0;
        *(float4*)&Bf[(long)node * M + q + 4] = o1;
    } else {
        f16x8 o;
#pragma unroll
        for (int c = 0; c < 8; ++c) o[c] = (f16)acc[c];
        *(f16x8*)&Bo[(long)node * M + q] = o;
    }
}

// ---------------- decode: out[i] = dot64(z[a], z[b]) ----------------
__global__ void k_decode(const float* __restrict__ z, const int* __restrict__ eli,
                         float* __restrict__ out, int L) {
    int t = blockIdx.x * blockDim.x + threadIdx.x;
    int e = t >> 4;
    int lane = t & 15;
    if (e >= L) return;
    int a = eli[e], b = eli[L + e];
    float4 va = *(const float4*)&z[(long)a * 64 + lane * 4];
    float4 vb = *(const float4*)&z[(long)b * 64 + lane * 4];
    float s = va.x * vb.x + va.y * vb.y + va.z * vb.z + va.w * vb.w;
    s += __shfl_xor(s, 1, 16);
    s += __shfl_xor(s, 2, 16);
    s += __shfl_xor(s, 4, 16);
    s += __shfl_xor(s, 8, 16);
    if (lane == 0) out[e] = s;
}

extern "C" void kernel_launch(void* const* d_in, const int* in_sizes, int n_in,
                              void* d_out, int out_size, void* d_ws, size_t ws_size,
                              hipStream_t stream) {
    const float* x   = (const float*)d_in[0];
    const float* W1  = (const float*)d_in[1];
    const float* b1  = (const float*)d_in[2];
    const float* W2  = (const float*)d_in[3];
    const float* b2  = (const float*)d_in[4];
    const float* W3  = (const float*)d_in[5];
    const float* b3  = (const float*)d_in[6];
    const int*   ei  = (const int*)d_in[7];
    const int*   eli = (const int*)d_in[8];
    float* out = (float*)d_out;

    char* ws = (char*)d_ws;
    float* dinv = (float*)ws;                  ws += 50048 * 4;
    f16*   A    = (f16*)ws;                    ws += (long)N_NODES * 128 * 2;
    f16*   B    = (f16*)ws;                    ws += (long)N_NODES * 128 * 2;
    float* z    = (float*)ws;                  ws += (long)N_NODES * 64 * 4;
    int*   cnt  = (int*)ws;                    ws += 50048 * 4;
    int*   cnt2 = (int*)ws;                    ws += 50048 * 4;   // contiguous with cnt
    int*   off  = (int*)ws;                    ws += 50048 * 4;
    unsigned short* csr = (unsigned short*)ws; ws += (long)N_EDGES * 2;
    int*   bsum = (int*)ws;                    ws += 256 * 4;
    f16*   WT1h = (f16*)ws;                    ws += 16384 * 2;
    f16*   WT1l = (f16*)ws;                    ws += 16384 * 2;
    f16*   WT2h = (f16*)ws;                    ws += 16384 * 2;
    f16*   WT2l = (f16*)ws;                    ws += 16384 * 2;
    f16*   WT3h = (f16*)ws;                    ws += 8192 * 2;
    f16*   WT3l = (f16*)ws;                    ws += 8192 * 2;

    const int* esrc = ei;
    const int* edst = ei + N_EDGES;

    const int NB = (N_NODES + 255) / 256;  // 196

    // zero cnt+cnt2 (2*50048 ints = 25024 int4), prep, scan chain, bucket
    k_zero   <<<98, 256, 0, stream>>>((int4*)cnt, 25024);
    k_prep   <<<25064, 256, 0, stream>>>(W1, W2, W3, WT1h, WT1l, WT2h, WT2l,
                                         WT3h, WT3l, edst, cnt);
    k_partial<<<NB, 256, 0, stream>>>(cnt, dinv, bsum, N_NODES);
    k_offsets<<<NB, 256, 0, stream>>>(cnt, bsum, off, N_NODES, NB);
    k_bucket <<<25000, 256, 0, stream>>>(esrc, edst, off, cnt2, csr);

    const int ga128 = (N_NODES * 16 + 255) / 256;   // 16 thr/node
    const int ga64  = (N_NODES * 8 + 255) / 256;    // 8 thr/node

    // layer 1 (x fp32 -> in-register fp16 split; 2-way col split)
    k_gemm1<<<ROW_BLOCKS * 2, 256, 0, stream>>>(x, WT1h, WT1l, dinv, A, N_NODES);
    k_gather<<<ga128, 256, 0, stream>>>(A, off, csr, dinv, b1, nullptr, B,
                                        N_NODES, 128, 4, 1, 1);
    // layer 2
    k_gemm23<128><<<ROW_BLOCKS * 2, 256, 0, stream>>>(B, WT2h, WT2l, dinv, A, N_NODES);
    k_gather<<<ga128, 256, 0, stream>>>(A, off, csr, dinv, b2, nullptr, B,
                                        N_NODES, 128, 4, 1, 1);
    // layer 3 (M=64, no relu, fp32 out)
    k_gemm23<64><<<ROW_BLOCKS * 2, 256, 0, stream>>>(B, WT3h, WT3l, dinv, A, N_NODES);
    k_gather<<<ga64, 256, 0, stream>>>(A, off, csr, dinv, b3, z, nullptr,
                                       N_NODES, 64, 3, 0, 0);

    // decode
    k_decode<<<(N_LABEL * 16 + 255) / 256, 256, 0, stream>>>(z, eli, out, N_LABEL);
}

// Round 12
// 216.821 us; speedup vs baseline: 1.6678x; 1.2444x over previous
//
#include <hip/hip_runtime.h>

#define N_NODES 50000
#define N_EDGES 800000
#define N_LABEL 200000
#define ROW_BLOCKS 782   // ceil(50000/64)

typedef __attribute__((ext_vector_type(4))) float f32x4;
typedef _Float16 f16;
typedef __attribute__((ext_vector_type(8))) _Float16 f16x8;

// ---------------- zero cnt+cnt2 ----------------
__global__ __launch_bounds__(256)
void k_zero(int4* __restrict__ p, int n4) {
    int i = blockIdx.x * 256 + threadIdx.x;
    if (i < n4) p[i] = int4{0, 0, 0, 0};
}

// ---------------- prep: W transpose/split fp16 hi+lo | XCD-partitioned deg_count ----------
__global__ __launch_bounds__(256)
void k_prep(const float* __restrict__ W1, const float* __restrict__ W2,
            const float* __restrict__ W3,
            f16* WT1h, f16* WT1l, f16* WT2h, f16* WT2l, f16* WT3h, f16* WT3l,
            const int* __restrict__ dst, int* cnt) {
    int b = blockIdx.x, tid = threadIdx.x;
    if (b < 64) {
        int t = b * 256 + tid;                 // < 16384
        int c = t >> 7, k = t & 127;
        float w = W1[k * 128 + c];
        f16 h = (f16)w;
        WT1h[c * 128 + k] = h; WT1l[c * 128 + k] = (f16)(w - (float)h);
        w = W2[k * 128 + c];
        h = (f16)w;
        WT2h[c * 128 + k] = h; WT2l[c * 128 + k] = (f16)(w - (float)h);
        if (c < 64) {
            w = W3[k * 64 + c];
            h = (f16)w;
            WT3h[c * 128 + k] = h; WT3l[c * 128 + k] = (f16)(w - (float)h);
        }
    } else {
        int vb = b - 64;                       // [0, 25000)
        int g = vb & 7;
        int i = (vb >> 3) * 256 + tid;         // < 800,000 exactly
        int d = dst[i];
        if ((unsigned)(d - g * 6250) < 6250u) atomicAdd(&cnt[d], 1);
    }
}

// ---------------- scan chain ----------------
__global__ __launch_bounds__(256)
void k_partial(const int* __restrict__ cnt, float* __restrict__ dinv,
               int* __restrict__ bsum, int N) {
    __shared__ int wsum[4];
    int b = blockIdx.x, t = threadIdx.x;
    int i = b * 256 + t;
    int v = (i < N) ? cnt[i] : 0;
    if (i < N) dinv[i] = rsqrtf((float)v + 1.0f);
    int s = v;
#pragma unroll
    for (int d = 1; d < 64; d <<= 1) s += __shfl_xor(s, d, 64);
    if ((t & 63) == 0) wsum[t >> 6] = s;
    __syncthreads();
    if (t == 0) bsum[b] = wsum[0] + wsum[1] + wsum[2] + wsum[3];
}

__global__ __launch_bounds__(256)
void k_offsets(const int* __restrict__ cnt, const int* __restrict__ bsum,
               int* __restrict__ off, int N, int NB) {
    __shared__ int wsum[4];
    __shared__ int add0_s;
    int b = blockIdx.x, t = threadIdx.x;
    int v0 = (t < b && t < NB) ? bsum[t] : 0;
    int s0 = v0;
#pragma unroll
    for (int d = 1; d < 64; d <<= 1) s0 += __shfl_xor(s0, d, 64);
    if ((t & 63) == 0) wsum[t >> 6] = s0;
    __syncthreads();
    if (t == 0) add0_s = wsum[0] + wsum[1] + wsum[2] + wsum[3];
    __syncthreads();
    int add = add0_s;
    __syncthreads();
    int i = b * 256 + t;
    int v = (i < N) ? cnt[i] : 0;
    int lane = t & 63, w = t >> 6;
    int sv = v;
#pragma unroll
    for (int d = 1; d < 64; d <<= 1) {
        int u = __shfl_up(sv, d, 64);
        if (lane >= d) sv += u;
    }
    if (lane == 63) wsum[w] = sv;
    __syncthreads();
    for (int ww = 0; ww < w; ++ww) add += wsum[ww];
    if (i < N) off[i + 1] = add + sv;
    if (i == 0) off[0] = 0;
}

// ---------------- XCD-partitioned bucket fill ----------------
__global__ __launch_bounds__(256)
void k_bucket(const int* __restrict__ srcv, const int* __restrict__ dstv,
              const int* __restrict__ off, int* cnt2, unsigned short* __restrict__ csr) {
    int vb = blockIdx.x;
    int g = vb & 7;
    int i = (vb >> 3) * 256 + threadIdx.x;   // < 800,000 exactly
    int d = dstv[i];
    if ((unsigned)(d - g * 6250) < 6250u) {
        int slot = off[d] + atomicAdd(&cnt2[d], 1);
        csr[slot] = (unsigned short)srcv[i];
    }
}

// ---------------- GEMM layer 1: fp32 x, in-register fp16 split, W in LDS ----------------
// grid = ROW_BLOCKS*2; block b: rows (b>>1)*64.., cols (b&1)*64..+64 (NCB=4)
// LDS: W half (64 cols x 128 k, hi+lo) padded to 136 f16/col -> ~2-way bank alias (free)
__global__ __launch_bounds__(256)
void k_gemm1(const float* __restrict__ x,
             const f16* __restrict__ WTh, const f16* __restrict__ WTl,
             const float* __restrict__ dinv, f16* __restrict__ A, int N) {
    constexpr int M = 128, NCB = 4;
    __shared__ f16 Hs[64 * 136];
    __shared__ f16 Ls[64 * 136];
    int b = blockIdx.x;
    int c0 = (b & 1) * 64;
    int t = threadIdx.x;

    // cooperative W stage: 64 cols x 128 f16 = 1024 16B-chunks per array, 4/thread
#pragma unroll
    for (int i = 0; i < 4; ++i) {
        int ch = t + i * 256;
        int col = ch >> 4;            // 0..63
        int kc = (ch & 15) * 8;       // 0..120
        *(f16x8*)&Hs[col * 136 + kc] = *(const f16x8*)&WTh[(long)(c0 + col) * 128 + kc];
        *(f16x8*)&Ls[col * 136 + kc] = *(const f16x8*)&WTl[(long)(c0 + col) * 128 + kc];
    }

    int wv = t >> 6, l = t & 63;
    int r0w = (b >> 1) * 64 + wv * 16;
    int arow = r0w + (l & 15);
    if (arow >= N) arow = N - 1;
    int kb = (l >> 4) * 8;

    f16x8 ah[4], al[4];
#pragma unroll
    for (int ks = 0; ks < 4; ++ks) {
        const float* xp = &x[(long)arow * 128 + ks * 32 + kb];
        float4 a0 = *(const float4*)xp;
        float4 a1 = *(const float4*)(xp + 4);
        float fv[8] = {a0.x, a0.y, a0.z, a0.w, a1.x, a1.y, a1.z, a1.w};
#pragma unroll
        for (int j = 0; j < 8; ++j) {
            f16 h = (f16)fv[j];
            ah[ks][j] = h;
            al[ks][j] = (f16)(fv[j] - (float)h);
        }
    }
    __syncthreads();

    f32x4 acc[NCB];
#pragma unroll
    for (int cb = 0; cb < NCB; ++cb) acc[cb] = f32x4{0.f, 0.f, 0.f, 0.f};
#pragma unroll
    for (int ks = 0; ks < 4; ++ks) {
#pragma unroll
        for (int cb = 0; cb < NCB; ++cb) {
            int wi = (cb * 16 + (l & 15)) * 136 + ks * 32 + kb;
            f16x8 bh = *(const f16x8*)&Hs[wi];
            f16x8 bl = *(const f16x8*)&Ls[wi];
            acc[cb] = __builtin_amdgcn_mfma_f32_16x16x32_f16(ah[ks], bh, acc[cb], 0, 0, 0);
            acc[cb] = __builtin_amdgcn_mfma_f32_16x16x32_f16(ah[ks], bl, acc[cb], 0, 0, 0);
            acc[cb] = __builtin_amdgcn_mfma_f32_16x16x32_f16(al[ks], bh, acc[cb], 0, 0, 0);
        }
    }
    // C/D layout: col = l&15, row = (l>>4)*4 + i   [verified m89]
    int rbase = r0w + (l >> 4) * 4;
    float dv[4];
#pragma unroll
    for (int i = 0; i < 4; ++i) dv[i] = (rbase + i < N) ? dinv[rbase + i] : 0.f;
#pragma unroll
    for (int cb = 0; cb < NCB; ++cb) {
#pragma unroll
        for (int i = 0; i < 4; ++i) {
            int r = rbase + i;
            if (r < N) A[(long)r * M + c0 + cb * 16 + (l & 15)] = (f16)(acc[cb][i] * dv[i]);
        }
    }
}

// ---------------- GEMM layers 2/3: B fp16 exact, 2 MFMAs, W in LDS ----------------
// grid = ROW_BLOCKS*2; NCB = M/32; LDS W half = (M/2) cols
template<int M>
__global__ __launch_bounds__(256)
void k_gemm23(const f16* __restrict__ B,
              const f16* __restrict__ WTh, const f16* __restrict__ WTl,
              const float* __restrict__ dinv, f16* __restrict__ A, int N) {
    constexpr int NCB = M / 32;
    constexpr int HC = M / 2;            // cols per block
    __shared__ f16 Hs[HC * 136];
    __shared__ f16 Ls[HC * 136];
    int b = blockIdx.x;
    int c0 = (b & 1) * HC;
    int t = threadIdx.x;

#pragma unroll
    for (int i = 0; i < HC / 16; ++i) {  // HC*128/8 chunks / 256 threads
        int ch = t + i * 256;
        int col = ch >> 4;
        int kc = (ch & 15) * 8;
        *(f16x8*)&Hs[col * 136 + kc] = *(const f16x8*)&WTh[(long)(c0 + col) * 128 + kc];
        *(f16x8*)&Ls[col * 136 + kc] = *(const f16x8*)&WTl[(long)(c0 + col) * 128 + kc];
    }

    int wv = t >> 6, l = t & 63;
    int r0w = (b >> 1) * 64 + wv * 16;
    int arow = r0w + (l & 15);
    if (arow >= N) arow = N - 1;
    int kb = (l >> 4) * 8;

    f16x8 a[4];
#pragma unroll
    for (int ks = 0; ks < 4; ++ks)
        a[ks] = *(const f16x8*)&B[(long)arow * 128 + ks * 32 + kb];
    __syncthreads();

    f32x4 acc[NCB];
#pragma unroll
    for (int cb = 0; cb < NCB; ++cb) acc[cb] = f32x4{0.f, 0.f, 0.f, 0.f};
#pragma unroll
    for (int ks = 0; ks < 4; ++ks) {
#pragma unroll
        for (int cb = 0; cb < NCB; ++cb) {
            int wi = (cb * 16 + (l & 15)) * 136 + ks * 32 + kb;
            f16x8 bh = *(const f16x8*)&Hs[wi];
            f16x8 bl = *(const f16x8*)&Ls[wi];
            acc[cb] = __builtin_amdgcn_mfma_f32_16x16x32_f16(a[ks], bh, acc[cb], 0, 0, 0);
            acc[cb] = __builtin_amdgcn_mfma_f32_16x16x32_f16(a[ks], bl, acc[cb], 0, 0, 0);
        }
    }
    int rbase = r0w + (l >> 4) * 4;
    float dv[4];
#pragma unroll
    for (int i = 0; i < 4; ++i) dv[i] = (rbase + i < N) ? dinv[rbase + i] : 0.f;
#pragma unroll
    for (int cb = 0; cb < NCB; ++cb) {
#pragma unroll
        for (int i = 0; i < 4; ++i) {
            int r = rbase + i;
            if (r < N) A[(long)r * M + c0 + cb * 16 + (l & 15)] = (f16)(acc[cb][i] * dv[i]);
        }
    }
}

// ---------------- gather + finish (A fp16, 8 ch/thread) ----------------
__global__ __launch_bounds__(256)
void k_gather(const f16* __restrict__ A, const int* __restrict__ off,
              const unsigned short* __restrict__ csr, const float* __restrict__ dinv,
              const float* __restrict__ bias, float* __restrict__ Bf,
              f16* __restrict__ Bo,
              int N, int M, int lg, int relu, int mode) {
    int t = blockIdx.x * blockDim.x + threadIdx.x;
    int node = t >> lg;
    if (node >= N) return;
    int q = (t & ((1 << lg) - 1)) << 3;   // 8 channels per thread
    const f16* Aq = A + q;

    float acc[8];
    {
        f16x8 v = *(const f16x8*)&Aq[(long)node * M];  // self-loop
#pragma unroll
        for (int c = 0; c < 8; ++c) acc[c] = (float)v[c];
    }
    int j = off[node], j1 = off[node + 1];
    for (; j + 8 <= j1; j += 8) {
        int s0 = csr[j + 0], s1 = csr[j + 1], s2 = csr[j + 2], s3 = csr[j + 3];
        int s4 = csr[j + 4], s5 = csr[j + 5], s6 = csr[j + 6], s7 = csr[j + 7];
        f16x8 v0 = *(const f16x8*)&Aq[(long)s0 * M];
        f16x8 v1 = *(const f16x8*)&Aq[(long)s1 * M];
        f16x8 v2 = *(const f16x8*)&Aq[(long)s2 * M];
        f16x8 v3 = *(const f16x8*)&Aq[(long)s3 * M];
        f16x8 v4 = *(const f16x8*)&Aq[(long)s4 * M];
        f16x8 v5 = *(const f16x8*)&Aq[(long)s5 * M];
        f16x8 v6 = *(const f16x8*)&Aq[(long)s6 * M];
        f16x8 v7 = *(const f16x8*)&Aq[(long)s7 * M];
#pragma unroll
        for (int c = 0; c < 8; ++c)
            acc[c] += ((float)v0[c] + (float)v1[c] + (float)v2[c] + (float)v3[c])
                    + ((float)v4[c] + (float)v5[c] + (float)v6[c] + (float)v7[c]);
    }
    for (; j + 2 <= j1; j += 2) {
        int s0 = csr[j + 0], s1 = csr[j + 1];
        f16x8 v0 = *(const f16x8*)&Aq[(long)s0 * M];
        f16x8 v1 = *(const f16x8*)&Aq[(long)s1 * M];
#pragma unroll
        for (int c = 0; c < 8; ++c) acc[c] += (float)v0[c] + (float)v1[c];
    }
    if (j < j1) {
        int s = csr[j];
        f16x8 v = *(const f16x8*)&Aq[(long)s * M];
#pragma unroll
        for (int c = 0; c < 8; ++c) acc[c] += (float)v[c];
    }

    float sc = dinv[node];
    float4 bb0 = *(const float4*)&bias[q];
    float4 bb1 = *(const float4*)&bias[q + 4];
    float bv[8] = {bb0.x, bb0.y, bb0.z, bb0.w, bb1.x, bb1.y, bb1.z, bb1.w};
#pragma unroll
    for (int c = 0; c < 8; ++c) {
        acc[c] = acc[c] * sc + bv[c];
        if (relu) acc[c] = fmaxf(acc[c], 0.f);
    }
    if (mode == 0) {
        float4 o0 = make_float4(acc[0], acc[1], acc[2], acc[3]);
        float4 o1 = make_float4(acc[4], acc[5], acc[6], acc[7]);
        *(float4*)&Bf[(long)node * M + q] = o0;
        *(float4*)&Bf[(long)node * M + q + 4] = o1;
    } else {
        f16x8 o;
#pragma unroll
        for (int c = 0; c < 8; ++c) o[c] = (f16)acc[c];
        *(f16x8*)&Bo[(long)node * M + q] = o;
    }
}

// ---------------- decode: out[i] = dot64(z[a], z[b]) ----------------
__global__ void k_decode(const float* __restrict__ z, const int* __restrict__ eli,
                         float* __restrict__ out, int L) {
    int t = blockIdx.x * blockDim.x + threadIdx.x;
    int e = t >> 4;
    int lane = t & 15;
    if (e >= L) return;
    int a = eli[e], b = eli[L + e];
    float4 va = *(const float4*)&z[(long)a * 64 + lane * 4];
    float4 vb = *(const float4*)&z[(long)b * 64 + lane * 4];
    float s = va.x * vb.x + va.y * vb.y + va.z * vb.z + va.w * vb.w;
    s += __shfl_xor(s, 1, 16);
    s += __shfl_xor(s, 2, 16);
    s += __shfl_xor(s, 4, 16);
    s += __shfl_xor(s, 8, 16);
    if (lane == 0) out[e] = s;
}

extern "C" void kernel_launch(void* const* d_in, const int* in_sizes, int n_in,
                              void* d_out, int out_size, void* d_ws, size_t ws_size,
                              hipStream_t stream) {
    const float* x   = (const float*)d_in[0];
    const float* W1  = (const float*)d_in[1];
    const float* b1  = (const float*)d_in[2];
    const float* W2  = (const float*)d_in[3];
    const float* b2  = (const float*)d_in[4];
    const float* W3  = (const float*)d_in[5];
    const float* b3  = (const float*)d_in[6];
    const int*   ei  = (const int*)d_in[7];
    const int*   eli = (const int*)d_in[8];
    float* out = (float*)d_out;

    char* ws = (char*)d_ws;
    float* dinv = (float*)ws;                  ws += 50048 * 4;
    f16*   A    = (f16*)ws;                    ws += (long)N_NODES * 128 * 2;
    f16*   B    = (f16*)ws;                    ws += (long)N_NODES * 128 * 2;
    float* z    = (float*)ws;                  ws += (long)N_NODES * 64 * 4;
    int*   cnt  = (int*)ws;                    ws += 50048 * 4;
    int*   cnt2 = (int*)ws;                    ws += 50048 * 4;   // contiguous with cnt
    int*   off  = (int*)ws;                    ws += 50048 * 4;
    unsigned short* csr = (unsigned short*)ws; ws += (long)N_EDGES * 2;
    int*   bsum = (int*)ws;                    ws += 256 * 4;
    f16*   WT1h = (f16*)ws;                    ws += 16384 * 2;
    f16*   WT1l = (f16*)ws;                    ws += 16384 * 2;
    f16*   WT2h = (f16*)ws;                    ws += 16384 * 2;
    f16*   WT2l = (f16*)ws;                    ws += 16384 * 2;
    f16*   WT3h = (f16*)ws;                    ws += 8192 * 2;
    f16*   WT3l = (f16*)ws;                    ws += 8192 * 2;

    const int* esrc = ei;
    const int* edst = ei + N_EDGES;

    const int NB = (N_NODES + 255) / 256;  // 196

    k_zero   <<<98, 256, 0, stream>>>((int4*)cnt, 25024);
    k_prep   <<<25064, 256, 0, stream>>>(W1, W2, W3, WT1h, WT1l, WT2h, WT2l,
                                         WT3h, WT3l, edst, cnt);
    k_partial<<<NB, 256, 0, stream>>>(cnt, dinv, bsum, N_NODES);
    k_offsets<<<NB, 256, 0, stream>>>(cnt, bsum, off, N_NODES, NB);
    k_bucket <<<25000, 256, 0, stream>>>(esrc, edst, off, cnt2, csr);

    const int ga128 = (N_NODES * 16 + 255) / 256;   // 16 thr/node
    const int ga64  = (N_NODES * 8 + 255) / 256;    // 8 thr/node

    // layer 1 (x fp32 -> in-register fp16 split; W in LDS; 2-way col split)
    k_gemm1<<<ROW_BLOCKS * 2, 256, 0, stream>>>(x, WT1h, WT1l, dinv, A, N_NODES);
    k_gather<<<ga128, 256, 0, stream>>>(A, off, csr, dinv, b1, nullptr, B,
                                        N_NODES, 128, 4, 1, 1);
    // layer 2
    k_gemm23<128><<<ROW_BLOCKS * 2, 256, 0, stream>>>(B, WT2h, WT2l, dinv, A, N_NODES);
    k_gather<<<ga128, 256, 0, stream>>>(A, off, csr, dinv, b2, nullptr, B,
                                        N_NODES, 128, 4, 1, 1);
    // layer 3 (M=64, no relu, fp32 out)
    k_gemm23<64><<<ROW_BLOCKS * 2, 256, 0, stream>>>(B, WT3h, WT3l, dinv, A, N_NODES);
    k_gather<<<ga64, 256, 0, stream>>>(A, off, csr, dinv, b3, z, nullptr,
                                       N_NODES, 64, 3, 0, 0);

    // decode
    k_decode<<<(N_LABEL * 16 + 255) / 256, 256, 0, stream>>>(z, eli, out, N_LABEL);
}